// Round 5
// baseline (353.025 us; speedup 1.0000x reference)
//
#include <hip/hip_runtime.h>
#include <hip/hip_bf16.h>
#include <math.h>

static constexpr int H = 480, W = 320, NH = 24, NW = 16, NB = 384;
static constexpr int HW = H * W;            // 153600
static constexpr int H2 = 240, W2 = 160;
static constexpr int HW2 = H2 * W2;         // 38400
static constexpr int H4 = 120, W4 = 80;
static constexpr int HW4 = H4 * W4;         // 9600
static constexpr int IMG_PIX = 3 * 1920 * 1280;  // 7372800

typedef __attribute__((ext_vector_type(8))) short short8;
typedef __attribute__((ext_vector_type(4))) float f32x4;
typedef __attribute__((ext_vector_type(8))) unsigned short ushort8;

// packed-weight region offsets (ushort elements)
static constexpr int WPK_CX2 = 0;          // [64][9][64]
static constexpr int WPK_CX3 = 36864;      // [48][9][64]
static constexpr int WPK_LT2 = 64512;      // [48][9][32] (ci>=16 zero)
static constexpr int WPK_F_CX = 78336;     // [64][32] (k>=27 zero)
static constexpr int WPK_F_LT = 80384;     // [16][32]
static constexpr int WPK_TOT = 80896;

__device__ __forceinline__ int iclamp(int v, int lo, int hi) {
    return v < lo ? lo : (v > hi ? hi : v);
}
__device__ __forceinline__ unsigned short f2bfu(float x) {
    __hip_bfloat16 h = __float2bfloat16(x);
    return *reinterpret_cast<unsigned short*>(&h);
}
__device__ __forceinline__ float bf2f(unsigned short u) {
    __hip_bfloat16 h = *reinterpret_cast<__hip_bfloat16*>(&u);
    return __bfloat162float(h);
}

// ---------------- weight pre-pack ----------------

__global__ __launch_bounds__(256) void k_pack(const float* __restrict__ cx_w2,
                                              const float* __restrict__ cx_w3,
                                              const float* __restrict__ lt_w2,
                                              const float* __restrict__ cx_w1,
                                              const float* __restrict__ lt_w1,
                                              unsigned short* __restrict__ wpk) {
    int i = blockIdx.x * 256 + threadIdx.x;
    if (i >= WPK_TOT) return;
    float v = 0.f;
    if (i < WPK_CX3) {
        int co = i / 576, t = (i / 64) % 9, ci = i % 64;
        v = cx_w2[(co * 64 + ci) * 9 + t];
    } else if (i < WPK_LT2) {
        int j = i - WPK_CX3;
        int co = j / 576, t = (j / 64) % 9, ci = j % 64;
        v = cx_w3[(co * 64 + ci) * 9 + t];
    } else if (i < WPK_F_CX) {
        int j = i - WPK_LT2;
        int co = j / 288, t = (j / 32) % 9, ci = j % 32;
        v = (ci < 16) ? lt_w2[(co * 16 + ci) * 9 + t] : 0.f;
    } else if (i < WPK_F_LT) {
        int j = i - WPK_F_CX;
        int co = j >> 5, k = j & 31;
        v = (k < 27) ? cx_w1[co * 27 + k] : 0.f;
    } else {
        int j = i - WPK_F_LT;
        int co = j >> 5, k = j & 31;
        v = (k < 27) ? lt_w1[co * 27 + k] : 0.f;
    }
    wpk[i] = f2bfu(v);
}

// ---------------- classifier (fp32, exact) ----------------

__global__ __launch_bounds__(256) void k_cls1(const float* __restrict__ x,
                                              const float* __restrict__ w,
                                              const float* __restrict__ b,
                                              float* __restrict__ out) {
    int p = blockIdx.x * 256 + threadIdx.x;
    if (p >= HW) return;
    int y = p / W, xx = p - y * W;
    float in[3][9];
#pragma unroll
    for (int ci = 0; ci < 3; ++ci)
#pragma unroll
        for (int dy = 0; dy < 3; ++dy) {
            int yy = iclamp(y + dy - 1, 0, H - 1);
#pragma unroll
            for (int dx = 0; dx < 3; ++dx) {
                int xc = iclamp(xx + dx - 1, 0, W - 1);
                in[ci][dy * 3 + dx] = x[ci * HW + yy * W + xc];
            }
        }
#pragma unroll
    for (int co = 0; co < 32; ++co) {
        float acc = b[co];
#pragma unroll
        for (int k = 0; k < 27; ++k) acc = fmaf(w[co * 27 + k], in[k / 9][k % 9], acc);
        out[co * HW + p] = fmaxf(acc, 0.f);
    }
}

// fused conv2(32->32, edge pad) + relu + 2x2 maxpool.
// wg = 16x16 pre-pool tile (600 wgs); pool via 32KB LDS tile.
__global__ __launch_bounds__(256) void k_cls2f(const float* __restrict__ in,
                                               const float* __restrict__ w,
                                               const float* __restrict__ b,
                                               float* __restrict__ out) {
    __shared__ float lds[32 * 256];
    int t = threadIdx.x;
    int tile = blockIdx.x;           // 30 x 20 tiles
    int ty = tile / 20, tx = tile - ty * 20;
    int ly = t >> 4, lx = t & 15;
    int y = ty * 16 + ly, xx = tx * 16 + lx;
    float acc[32];
#pragma unroll
    for (int co = 0; co < 32; ++co) acc[co] = b[co];
    for (int ci = 0; ci < 32; ++ci) {
        float v[9];
#pragma unroll
        for (int dy = 0; dy < 3; ++dy) {
            int yy = iclamp(y + dy - 1, 0, H - 1);
#pragma unroll
            for (int dx = 0; dx < 3; ++dx) {
                int xc = iclamp(xx + dx - 1, 0, W - 1);
                v[dy * 3 + dx] = in[ci * HW + yy * W + xc];
            }
        }
#pragma unroll
        for (int co = 0; co < 32; ++co) {
            const float* wp = w + co * 288 + ci * 9;
#pragma unroll
            for (int k = 0; k < 9; ++k) acc[co] = fmaf(wp[k], v[k], acc[co]);
        }
    }
#pragma unroll
    for (int co = 0; co < 32; ++co) lds[co * 256 + t] = fmaxf(acc[co], 0.f);
    __syncthreads();
    // 2048 pooled outputs per wg -> 8 per thread
#pragma unroll
    for (int k = 0; k < 8; ++k) {
        int o = t + k * 256;
        int co = o >> 6, rem = o & 63;
        int py = rem >> 3, px = rem & 7;
        const float* lp = lds + co * 256 + py * 32 + px * 2;
        float m = fmaxf(fmaxf(lp[0], lp[1]), fmaxf(lp[16], lp[17]));
        out[co * HW2 + (ty * 8 + py) * W2 + tx * 8 + px] = m;
    }
}

// conv3 32->16 edge pad at 240x160, ci-split x2, fp32 partials (no relu).
__global__ __launch_bounds__(256) void k_cls3(const float* __restrict__ in,
                                              const float* __restrict__ w,
                                              const float* __restrict__ b,
                                              float* __restrict__ p3) {
    int p = blockIdx.x * 256 + threadIdx.x;
    if (p >= HW2) return;
    int s = blockIdx.y;  // 0..1
    int y = p / W2, xx = p - y * W2;
    float acc[16];
#pragma unroll
    for (int co = 0; co < 16; ++co) acc[co] = s ? 0.f : b[co];
    for (int cil = 0; cil < 16; ++cil) {
        int ci = s * 16 + cil;
        float v[9];
#pragma unroll
        for (int dy = 0; dy < 3; ++dy) {
            int yy = iclamp(y + dy - 1, 0, H2 - 1);
#pragma unroll
            for (int dx = 0; dx < 3; ++dx) {
                int xc = iclamp(xx + dx - 1, 0, W2 - 1);
                v[dy * 3 + dx] = in[ci * HW2 + yy * W2 + xc];
            }
        }
#pragma unroll
        for (int co = 0; co < 16; ++co)
#pragma unroll
            for (int k = 0; k < 9; ++k)
                acc[co] = fmaf(w[co * 288 + ci * 9 + k], v[k], acc[co]);
    }
#pragma unroll
    for (int co = 0; co < 16; ++co) p3[(s * 16 + co) * HW2 + p] = acc[co];
}

// fused (partial-sum + relu) -> conv4(16->8, edge pad) + relu + 2x2 maxpool.
// wg = 16x16 pre-pool tile at 240x160 (150 wgs); pool via 8KB LDS.
__global__ __launch_bounds__(256) void k_cls4f(const float* __restrict__ p3,
                                               const float* __restrict__ w,
                                               const float* __restrict__ b,
                                               float* __restrict__ out) {
    __shared__ float lds[8 * 256];
    int t = threadIdx.x;
    int tile = blockIdx.x;           // 15 x 10 tiles
    int ty = tile / 10, tx = tile - ty * 10;
    int ly = t >> 4, lx = t & 15;
    int y = ty * 16 + ly, xx = tx * 16 + lx;
    float acc[8];
#pragma unroll
    for (int co = 0; co < 8; ++co) acc[co] = b[co];
    for (int ci = 0; ci < 16; ++ci) {
        float v[9];
#pragma unroll
        for (int dy = 0; dy < 3; ++dy) {
            int yy = iclamp(y + dy - 1, 0, H2 - 1);
#pragma unroll
            for (int dx = 0; dx < 3; ++dx) {
                int xc = iclamp(xx + dx - 1, 0, W2 - 1);
                int idx = ci * HW2 + yy * W2 + xc;
                v[dy * 3 + dx] = fmaxf(p3[idx] + p3[idx + 16 * HW2], 0.f);
            }
        }
#pragma unroll
        for (int co = 0; co < 8; ++co) {
            const float* wp = w + co * 144 + ci * 9;
#pragma unroll
            for (int k = 0; k < 9; ++k) acc[co] = fmaf(wp[k], v[k], acc[co]);
        }
    }
#pragma unroll
    for (int co = 0; co < 8; ++co) lds[co * 256 + t] = fmaxf(acc[co], 0.f);
    __syncthreads();
    // 512 pooled outputs per wg -> 2 per thread
#pragma unroll
    for (int k = 0; k < 2; ++k) {
        int o = t + k * 256;
        int co = o >> 6, rem = o & 63;
        int py = rem >> 3, px = rem & 7;
        const float* lp = lds + co * 256 + py * 32 + px * 2;
        float m = fmaxf(fmaxf(lp[0], lp[1]), fmaxf(lp[16], lp[17]));
        out[co * HW4 + (ty * 8 + py) * W4 + tx * 8 + px] = m;
    }
}

__global__ __launch_bounds__(384) void k_cls5(const float* __restrict__ in,
                                              const float* __restrict__ w,
                                              const float* __restrict__ b,
                                              float* __restrict__ clsv,
                                              float* __restrict__ out_cls) {
    int tid = threadIdx.x;
    if (tid >= NB) return;
    int oy = tid / NW, ox = tid - oy * NW;
    float s = b[0];
    for (int ci = 0; ci < 8; ++ci)
#pragma unroll
        for (int ky = 0; ky < 5; ++ky)
#pragma unroll
            for (int kx = 0; kx < 5; ++kx)
                s = fmaf(w[ci * 25 + ky * 5 + kx],
                         in[ci * HW4 + (oy * 5 + ky) * W4 + (ox * 5 + kx)], s);
    float sig = 1.f / (1.f + expf(-s));
    clsv[tid] = sig;
    out_cls[tid] = sig;
}

// ---------------- block branches: bf16 MFMA ----------------

__global__ __launch_bounds__(512, 2) void k_first(const float* __restrict__ x,
                                                  const unsigned short* __restrict__ wpk,
                                                  const float* __restrict__ bl,
                                                  const float* __restrict__ bc,
                                                  const float* __restrict__ clsv,
                                                  int b0, __hip_bfloat16* __restrict__ t1) {
    extern __shared__ unsigned short sh[];
    unsigned short* A = sh;                 // 1024*40
    unsigned short* halo = sh + 1024 * 40;  // 3*1156
    int bL = blockIdx.x, b = b0 + bL;
    bool cx = clsv[b] > 0.5f;
    int bh = b / NW, bw = b - bh * NW;
    int tid = threadIdx.x;
    for (int i = tid; i < 3 * 1156; i += 512) {
        int ci = i / 1156, rem = i - ci * 1156;
        int ry = rem / 34, rx = rem - ry * 34;
        int yg = bh * 20 + ry - 7, xg = bw * 20 + rx - 7;
        float v = ((unsigned)yg < (unsigned)H && (unsigned)xg < (unsigned)W)
                      ? x[ci * HW + yg * W + xg] : 0.f;
        halo[i] = f2bfu(v);
    }
    __syncthreads();
    for (int v = tid; v < 1024 * 32; v += 512) {
        int p = v >> 5, k = v & 31;
        unsigned short val = 0;
        if (k < 27) {
            int ci = k / 9, t = k - ci * 9;
            int dy = t / 3, dx = t - dy * 3;
            int y = p >> 5, xx = p & 31;
            val = halo[ci * 1156 + (y + dy) * 34 + (xx + dx)];
        }
        A[p * 40 + k] = val;
    }
    __syncthreads();
    int lane = tid & 63, wave = tid >> 6;
    int col = lane & 15, kq = lane >> 4;
    const unsigned short* wf = wpk + (cx ? WPK_F_CX : WPK_F_LT);
    const float* bi = cx ? bc : bl;
    int nT = cx ? 4 : 1;
    __hip_bfloat16* outb = t1 + (long)bL * 65536;
    for (int nt = 0; nt < nT; ++nt) {
        int co = nt * 16 + col;
        short8 Bf = *(const short8*)(wf + co * 32 + kq * 8);
        float bv = bi[co];
#pragma unroll 1
        for (int i = 0; i < 8; ++i) {
            int mt = wave * 8 + i;
            short8 a = *(const short8*)(A + (mt * 16 + col) * 40 + kq * 8);
            f32x4 acc = {bv, bv, bv, bv};
            acc = __builtin_amdgcn_mfma_f32_16x16x32_bf16(a, Bf, acc, 0, 0, 0);
            int prow = mt * 16 + kq * 4;
#pragma unroll
            for (int r = 0; r < 4; ++r)
                outb[(prow + r) * 64 + co] = __float2bfloat16(fmaxf(acc[r], 0.f));
        }
    }
}

// taps-outer conv over one 32x32 block from XOR-swizzled LDS.
template <int CINP, int NT, int GOUT, bool RELU>
__device__ __forceinline__ void conv_mfma(const unsigned short* __restrict__ sh,
                                          const unsigned short* __restrict__ wpk,
                                          const float* __restrict__ bias,
                                          unsigned short* __restrict__ outg, int tid) {
    constexpr int KC = CINP / 32;
    int lane = tid & 63, wave = tid >> 6;
    int col = lane & 15, kq = lane >> 4;
    f32x4 acc[8][NT];
#pragma unroll
    for (int nt = 0; nt < NT; ++nt) {
        float bv = bias[nt * 16 + col];
#pragma unroll
        for (int i = 0; i < 8; ++i) acc[i][nt] = f32x4{bv, bv, bv, bv};
    }
#pragma unroll 1
    for (int t = 0; t < 9; ++t) {
        int dy = t / 3, dx = t - dy * 3;
        short8 B[NT][KC];
#pragma unroll
        for (int nt = 0; nt < NT; ++nt)
#pragma unroll
            for (int kc = 0; kc < KC; ++kc)
                B[nt][kc] = *(const short8*)(wpk + ((nt * 16 + col) * 9 + t) * CINP +
                                             kc * 32 + kq * 8);
#pragma unroll
        for (int i = 0; i < 8; ++i) {
            int mt = wave * 8 + i;
            int yp = (mt >> 1) + dy - 1;
            if ((unsigned)yp > 31u) continue;  // wave-uniform skip
            int xs = ((mt & 1) << 4) + col + dx - 1;
            bool xv = (unsigned)xs < 32u;
            int xc = xs < 0 ? 0 : (xs > 31 ? 31 : xs);
            int pr = yp * 32 + xc;
#pragma unroll
            for (int kc = 0; kc < KC; ++kc) {
                int c = kc * 4 + kq;
                int cs = (CINP == 64) ? (c ^ (pr & 7)) : (c ^ ((pr >> 1) & 3));
                short8 a = *(const short8*)(sh + pr * CINP + cs * 8);
                if (!xv) a = short8{0, 0, 0, 0, 0, 0, 0, 0};
#pragma unroll
                for (int nt = 0; nt < NT; ++nt)
                    acc[i][nt] = __builtin_amdgcn_mfma_f32_16x16x32_bf16(a, B[nt][kc],
                                                                         acc[i][nt], 0, 0, 0);
            }
        }
    }
#pragma unroll
    for (int i = 0; i < 8; ++i) {
        int prow = (wave * 8 + i) * 16 + kq * 4;
#pragma unroll
        for (int nt = 0; nt < NT; ++nt) {
            int co = nt * 16 + col;
#pragma unroll
            for (int r = 0; r < 4; ++r) {
                float v = acc[i][nt][r];
                if (RELU) v = fmaxf(v, 0.f);
                outg[(prow + r) * GOUT + co] = f2bfu(v);
            }
        }
    }
}

// merged second conv: cx blocks do 64->64 (t1->t2, relu); lt blocks do 16->48 (t1->t3).
__global__ __launch_bounds__(512, 2) void k_b2(const __hip_bfloat16* __restrict__ t1,
                                               const unsigned short* __restrict__ wpk,
                                               const float* __restrict__ cx_b2,
                                               const float* __restrict__ lt_b2,
                                               const float* __restrict__ clsv, int b0,
                                               __hip_bfloat16* __restrict__ t2,
                                               __hip_bfloat16* __restrict__ t3) {
    extern __shared__ unsigned short sh[];
    int bL = blockIdx.x;
    bool cx = clsv[b0 + bL] > 0.5f;
    int tid = threadIdx.x;
    const unsigned short* inb = (const unsigned short*)t1 + (long)bL * 65536;
    if (cx) {
        for (int u = tid; u < 8192; u += 512) {
            int p = u >> 3, c = u & 7;
            *(ushort8*)(sh + p * 64 + (c ^ (p & 7)) * 8) =
                *(const ushort8*)(inb + p * 64 + c * 8);
        }
        __syncthreads();
        conv_mfma<64, 4, 64, true>(sh, wpk + WPK_CX2, cx_b2,
                                   (unsigned short*)t2 + (long)bL * 65536, tid);
    } else {
        ushort8 z = {0, 0, 0, 0, 0, 0, 0, 0};
        for (int u = tid; u < 4096; u += 512) {
            int p = u >> 2, c = u & 3;
            ushort8 v = (c < 2) ? *(const ushort8*)(inb + p * 64 + c * 8) : z;
            *(ushort8*)(sh + p * 32 + (c ^ ((p >> 1) & 3)) * 8) = v;
        }
        __syncthreads();
        conv_mfma<32, 3, 48, false>(sh, wpk + WPK_LT2, lt_b2,
                                    (unsigned short*)t3 + (long)bL * 49152, tid);
    }
}

// third conv, cx only: 64->48 (t2->t3).
__global__ __launch_bounds__(512, 2) void k_b3(const __hip_bfloat16* __restrict__ t2,
                                               const unsigned short* __restrict__ wpk,
                                               const float* __restrict__ cx_b3,
                                               const float* __restrict__ clsv, int b0,
                                               __hip_bfloat16* __restrict__ t3) {
    extern __shared__ unsigned short sh[];
    int bL = blockIdx.x;
    if (!(clsv[b0 + bL] > 0.5f)) return;
    int tid = threadIdx.x;
    const unsigned short* inb = (const unsigned short*)t2 + (long)bL * 65536;
    for (int u = tid; u < 8192; u += 512) {
        int p = u >> 3, c = u & 7;
        *(ushort8*)(sh + p * 64 + (c ^ (p & 7)) * 8) = *(const ushort8*)(inb + p * 64 + c * 8);
    }
    __syncthreads();
    conv_mfma<64, 3, 48, false>(sh, wpk + WPK_CX3, cx_b3,
                                (unsigned short*)t3 + (long)bL * 49152, tid);
}

// pixel shuffle + clip + crop + reassemble from bf16 t3 [p][48]
__global__ __launch_bounds__(256) void k_assemble(const unsigned short* __restrict__ t3,
                                                  int b0, int nb, float* __restrict__ out) {
    int idx = blockIdx.x * 256 + threadIdx.x;
    if (idx >= nb * 19200) return;
    int bL = idx / 19200;
    int rem = idx - bL * 19200;
    int ch = rem / 6400;
    int rem2 = rem - ch * 6400;
    int r = rem2 / 80, s = rem2 - r * 80;
    int b = b0 + bL;
    int bh = b / NW, bw = b - bh * NW;
    int yy = r + 24, xx = s + 24;
    int pc = ch * 16 + (yy & 3) * 4 + (xx & 3);
    float v = bf2f(t3[(long)bL * 49152 + ((yy >> 2) * 32 + (xx >> 2)) * 48 + pc]);
    v = fminf(fmaxf(v, 0.f), 1.f);
    out[ch * (1920 * 1280) + (bh * 80 + r) * 1280 + (bw * 80 + s)] = v;
}

extern "C" void kernel_launch(void* const* d_in, const int* in_sizes, int n_in,
                              void* d_out, int out_size, void* d_ws, size_t ws_size,
                              hipStream_t stream) {
    const float* x      = (const float*)d_in[0];
    const float* cls_w1 = (const float*)d_in[1];
    const float* cls_b1 = (const float*)d_in[2];
    const float* cls_w2 = (const float*)d_in[3];
    const float* cls_b2 = (const float*)d_in[4];
    const float* cls_w3 = (const float*)d_in[5];
    const float* cls_b3 = (const float*)d_in[6];
    const float* cls_w4 = (const float*)d_in[7];
    const float* cls_b4 = (const float*)d_in[8];
    const float* cls_w5 = (const float*)d_in[9];
    const float* cls_b5 = (const float*)d_in[10];
    const float* lt_w1  = (const float*)d_in[11];
    const float* lt_b1  = (const float*)d_in[12];
    const float* lt_w2  = (const float*)d_in[13];
    const float* lt_b2  = (const float*)d_in[14];
    const float* cx_w1  = (const float*)d_in[15];
    const float* cx_b1  = (const float*)d_in[16];
    const float* cx_w2  = (const float*)d_in[17];
    const float* cx_b2  = (const float*)d_in[18];
    const float* cx_w3  = (const float*)d_in[19];
    const float* cx_b3  = (const float*)d_in[20];

    float* ws = (float*)d_ws;
    float* out = (float*)d_out;

    // persistent small buffers
    size_t off = 0;
    float* c2 = ws + off;   off += (size_t)32 * HW2;   // 1,228,800
    float* c4 = ws + off;   off += (size_t)8 * HW4;    //    76,800
    float* clsv = ws + off; off += 384;
    unsigned short* wpk = (unsigned short*)(ws + off); off += (WPK_TOT + 1) / 2;
    size_t fixed = off;

    // scratch region: c1 (classifier phase), p3 (aliases c1 after it's dead),
    // then t1/t2/t3 (block phase, aliases both).
    float* c1 = ws + fixed;                      // 32*HW fl
    float* p3 = ws + fixed;                      // 32*HW2 fl (after c1 dead)
    long avail_bytes = (long)ws_size - (long)fixed * 4;
    long per_block_bytes = (65536 + 65536 + 49152) * 2;  // 360448
    long cmax = avail_bytes / per_block_bytes;
    int chunk = (int)(cmax < 1 ? 1 : (cmax > NB ? NB : cmax));
    __hip_bfloat16* t1 = (__hip_bfloat16*)(ws + fixed);
    __hip_bfloat16* t2 = t1 + (long)chunk * 65536;
    __hip_bfloat16* t3 = t2 + (long)chunk * 65536;

    (void)hipFuncSetAttribute((const void*)k_first,
                              hipFuncAttributeMaxDynamicSharedMemorySize, 88856);
    (void)hipFuncSetAttribute((const void*)k_b2,
                              hipFuncAttributeMaxDynamicSharedMemorySize, 131072);
    (void)hipFuncSetAttribute((const void*)k_b3,
                              hipFuncAttributeMaxDynamicSharedMemorySize, 131072);

    k_pack<<<(WPK_TOT + 255) / 256, 256, 0, stream>>>(cx_w2, cx_w3, lt_w2, cx_w1, lt_w1, wpk);
    k_cls1<<<(HW + 255) / 256, 256, 0, stream>>>(x, cls_w1, cls_b1, c1);
    k_cls2f<<<600, 256, 0, stream>>>(c1, cls_w2, cls_b2, c2);
    k_cls3<<<dim3((HW2 + 255) / 256, 2), 256, 0, stream>>>(c2, cls_w3, cls_b3, p3);
    k_cls4f<<<150, 256, 0, stream>>>(p3, cls_w4, cls_b4, c4);
    k_cls5<<<1, 384, 0, stream>>>(c4, cls_w5, cls_b5, clsv, out + IMG_PIX);

    for (int b0 = 0; b0 < NB; b0 += chunk) {
        int n = chunk < (NB - b0) ? chunk : (NB - b0);
        k_first<<<n, 512, 88856, stream>>>(x, wpk, lt_b1, cx_b1, clsv, b0, t1);
        k_b2<<<n, 512, 131072, stream>>>(t1, wpk, cx_b2, lt_b2, clsv, b0, t2, t3);
        k_b3<<<n, 512, 131072, stream>>>(t2, wpk, cx_b3, clsv, b0, t3);
        k_assemble<<<(n * 19200 + 255) / 256, 256, 0, stream>>>(
            (const unsigned short*)t3, b0, n, out);
    }
}

// Round 6
// 322.370 us; speedup vs baseline: 1.0951x; 1.0951x over previous
//
#include <hip/hip_runtime.h>
#include <hip/hip_bf16.h>
#include <math.h>

static constexpr int H = 480, W = 320, NH = 24, NW = 16, NB = 384;
static constexpr int HW = H * W;            // 153600
static constexpr int H2 = 240, W2 = 160;
static constexpr int HW2 = H2 * W2;         // 38400
static constexpr int H4 = 120, W4 = 80;
static constexpr int HW4 = H4 * W4;         // 9600
static constexpr int IMG_PIX = 3 * 1920 * 1280;  // 7372800

typedef __attribute__((ext_vector_type(8))) short short8;
typedef __attribute__((ext_vector_type(4))) float f32x4;
typedef __attribute__((ext_vector_type(8))) unsigned short ushort8;

// packed-weight region offsets (ushort elements)
static constexpr int WPK_CX2 = 0;          // [64][9][64]
static constexpr int WPK_CX3 = 36864;      // [48][9][64]
static constexpr int WPK_LT2 = 64512;      // [48][9][32] (ci>=16 zero)
static constexpr int WPK_F_CX = 78336;     // [64][32] (k>=27 zero)
static constexpr int WPK_F_LT = 80384;     // [16][32]
static constexpr int WPK_TOT = 80896;

__device__ __forceinline__ int iclamp(int v, int lo, int hi) {
    return v < lo ? lo : (v > hi ? hi : v);
}
__device__ __forceinline__ unsigned short f2bfu(float x) {
    __hip_bfloat16 h = __float2bfloat16(x);
    return *reinterpret_cast<unsigned short*>(&h);
}
__device__ __forceinline__ float bf2f(unsigned short u) {
    __hip_bfloat16 h = *reinterpret_cast<__hip_bfloat16*>(&u);
    return __bfloat162float(h);
}

// ---------------- weight pre-pack ----------------

__global__ __launch_bounds__(256) void k_pack(const float* __restrict__ cx_w2,
                                              const float* __restrict__ cx_w3,
                                              const float* __restrict__ lt_w2,
                                              const float* __restrict__ cx_w1,
                                              const float* __restrict__ lt_w1,
                                              unsigned short* __restrict__ wpk) {
    int i = blockIdx.x * 256 + threadIdx.x;
    if (i >= WPK_TOT) return;
    float v = 0.f;
    if (i < WPK_CX3) {
        int co = i / 576, t = (i / 64) % 9, ci = i % 64;
        v = cx_w2[(co * 64 + ci) * 9 + t];
    } else if (i < WPK_LT2) {
        int j = i - WPK_CX3;
        int co = j / 576, t = (j / 64) % 9, ci = j % 64;
        v = cx_w3[(co * 64 + ci) * 9 + t];
    } else if (i < WPK_F_CX) {
        int j = i - WPK_LT2;
        int co = j / 288, t = (j / 32) % 9, ci = j % 32;
        v = (ci < 16) ? lt_w2[(co * 16 + ci) * 9 + t] : 0.f;
    } else if (i < WPK_F_LT) {
        int j = i - WPK_F_CX;
        int co = j >> 5, k = j & 31;
        v = (k < 27) ? cx_w1[co * 27 + k] : 0.f;
    } else {
        int j = i - WPK_F_LT;
        int co = j >> 5, k = j & 31;
        v = (k < 27) ? lt_w1[co * 27 + k] : 0.f;
    }
    wpk[i] = f2bfu(v);
}

// ---------------- classifier (fp32, exact) ----------------

// fused conv1(3->32) -> relu -> conv2(32->32, edge pad) -> relu -> 2x2 maxpool.
// wg = 16x16 pre-pool tile (600 wgs). conv1 computed into an 18x18 LDS halo
// (bit-exact same fmaf order as the standalone version), conv2 reads LDS,
// pool reuses the same LDS after a barrier.
__global__ __launch_bounds__(256, 3) void k_cls12f(const float* __restrict__ x,
                                                   const float* __restrict__ w1,
                                                   const float* __restrict__ b1,
                                                   const float* __restrict__ w2,
                                                   const float* __restrict__ b2,
                                                   float* __restrict__ out) {
    __shared__ float c1t[32 * 324];  // 41472 B; [ci][18*18]; aliased for pool
    int t = threadIdx.x;
    int tile = blockIdx.x;           // 30 x 20 tiles
    int ty = tile / 20, tx = tile - ty * 20;
    // stage conv1 output on the 18x18 halo (clamped to image)
    for (int pos = t; pos < 324; pos += 256) {
        int hy = ty * 16 + pos / 18 - 1, hx = tx * 16 + pos % 18 - 1;
        int chy = iclamp(hy, 0, H - 1), chx = iclamp(hx, 0, W - 1);
        float in[27];
#pragma unroll
        for (int ci = 0; ci < 3; ++ci)
#pragma unroll
            for (int dy = 0; dy < 3; ++dy) {
                int yy = iclamp(chy + dy - 1, 0, H - 1);
#pragma unroll
                for (int dx = 0; dx < 3; ++dx) {
                    int xc = iclamp(chx + dx - 1, 0, W - 1);
                    in[ci * 9 + dy * 3 + dx] = x[ci * HW + yy * W + xc];
                }
            }
#pragma unroll
        for (int co = 0; co < 32; ++co) {
            float acc = b1[co];
#pragma unroll
            for (int k = 0; k < 27; ++k) acc = fmaf(w1[co * 27 + k], in[k], acc);
            c1t[co * 324 + pos] = fmaxf(acc, 0.f);
        }
    }
    __syncthreads();
    int ly = t >> 4, lx = t & 15;
    float acc[32];
#pragma unroll
    for (int co = 0; co < 32; ++co) acc[co] = b2[co];
    for (int ci = 0; ci < 32; ++ci) {
        float v[9];
#pragma unroll
        for (int dy = 0; dy < 3; ++dy)
#pragma unroll
            for (int dx = 0; dx < 3; ++dx)
                v[dy * 3 + dx] = c1t[ci * 324 + (ly + dy) * 18 + (lx + dx)];
#pragma unroll
        for (int co = 0; co < 32; ++co) {
            const float* wp = w2 + co * 288 + ci * 9;
#pragma unroll
            for (int k = 0; k < 9; ++k) acc[co] = fmaf(wp[k], v[k], acc[co]);
        }
    }
    __syncthreads();  // all c1t reads complete; safe to alias
    float* pool = c1t;
#pragma unroll
    for (int co = 0; co < 32; ++co) pool[co * 256 + t] = fmaxf(acc[co], 0.f);
    __syncthreads();
    // 2048 pooled outputs per wg -> 8 per thread
#pragma unroll
    for (int k = 0; k < 8; ++k) {
        int o = t + k * 256;
        int co = o >> 6, rem = o & 63;
        int py = rem >> 3, px = rem & 7;
        const float* lp = pool + co * 256 + py * 32 + px * 2;
        float m = fmaxf(fmaxf(lp[0], lp[1]), fmaxf(lp[16], lp[17]));
        out[co * HW2 + (ty * 8 + py) * W2 + tx * 8 + px] = m;
    }
}

// conv3 32->16 edge pad at 240x160, ci-split x2, fp32 partials (no relu).
__global__ __launch_bounds__(256, 4) void k_cls3(const float* __restrict__ in,
                                                 const float* __restrict__ w,
                                                 const float* __restrict__ b,
                                                 float* __restrict__ p3) {
    int p = blockIdx.x * 256 + threadIdx.x;
    if (p >= HW2) return;
    int s = blockIdx.y;  // 0..1
    int y = p / W2, xx = p - y * W2;
    float acc[16];
#pragma unroll
    for (int co = 0; co < 16; ++co) acc[co] = s ? 0.f : b[co];
    for (int cil = 0; cil < 16; ++cil) {
        int ci = s * 16 + cil;
        float v[9];
#pragma unroll
        for (int dy = 0; dy < 3; ++dy) {
            int yy = iclamp(y + dy - 1, 0, H2 - 1);
#pragma unroll
            for (int dx = 0; dx < 3; ++dx) {
                int xc = iclamp(xx + dx - 1, 0, W2 - 1);
                v[dy * 3 + dx] = in[ci * HW2 + yy * W2 + xc];
            }
        }
#pragma unroll
        for (int co = 0; co < 16; ++co)
#pragma unroll
            for (int k = 0; k < 9; ++k)
                acc[co] = fmaf(w[co * 288 + ci * 9 + k], v[k], acc[co]);
    }
#pragma unroll
    for (int co = 0; co < 16; ++co) p3[(s * 16 + co) * HW2 + p] = acc[co];
}

// fused (partial-sum + relu) -> conv4(16->8, edge pad) + relu + 2x2 maxpool.
__global__ __launch_bounds__(256, 4) void k_cls4f(const float* __restrict__ p3,
                                                  const float* __restrict__ w,
                                                  const float* __restrict__ b,
                                                  float* __restrict__ out) {
    __shared__ float lds[8 * 256];
    int t = threadIdx.x;
    int tile = blockIdx.x;           // 15 x 10 tiles
    int ty = tile / 10, tx = tile - ty * 10;
    int ly = t >> 4, lx = t & 15;
    int y = ty * 16 + ly, xx = tx * 16 + lx;
    float acc[8];
#pragma unroll
    for (int co = 0; co < 8; ++co) acc[co] = b[co];
    for (int ci = 0; ci < 16; ++ci) {
        float v[9];
#pragma unroll
        for (int dy = 0; dy < 3; ++dy) {
            int yy = iclamp(y + dy - 1, 0, H2 - 1);
#pragma unroll
            for (int dx = 0; dx < 3; ++dx) {
                int xc = iclamp(xx + dx - 1, 0, W2 - 1);
                int idx = ci * HW2 + yy * W2 + xc;
                v[dy * 3 + dx] = fmaxf(p3[idx] + p3[idx + 16 * HW2], 0.f);
            }
        }
#pragma unroll
        for (int co = 0; co < 8; ++co) {
            const float* wp = w + co * 144 + ci * 9;
#pragma unroll
            for (int k = 0; k < 9; ++k) acc[co] = fmaf(wp[k], v[k], acc[co]);
        }
    }
#pragma unroll
    for (int co = 0; co < 8; ++co) lds[co * 256 + t] = fmaxf(acc[co], 0.f);
    __syncthreads();
#pragma unroll
    for (int k = 0; k < 2; ++k) {
        int o = t + k * 256;
        int co = o >> 6, rem = o & 63;
        int py = rem >> 3, px = rem & 7;
        const float* lp = lds + co * 256 + py * 32 + px * 2;
        float m = fmaxf(fmaxf(lp[0], lp[1]), fmaxf(lp[16], lp[17]));
        out[co * HW4 + (ty * 8 + py) * W4 + tx * 8 + px] = m;
    }
}

__global__ __launch_bounds__(384) void k_cls5(const float* __restrict__ in,
                                              const float* __restrict__ w,
                                              const float* __restrict__ b,
                                              float* __restrict__ clsv,
                                              float* __restrict__ out_cls) {
    int tid = threadIdx.x;
    if (tid >= NB) return;
    int oy = tid / NW, ox = tid - oy * NW;
    float s = b[0];
    for (int ci = 0; ci < 8; ++ci)
#pragma unroll
        for (int ky = 0; ky < 5; ++ky)
#pragma unroll
            for (int kx = 0; kx < 5; ++kx)
                s = fmaf(w[ci * 25 + ky * 5 + kx],
                         in[ci * HW4 + (oy * 5 + ky) * W4 + (ox * 5 + kx)], s);
    float sig = 1.f / (1.f + expf(-s));
    clsv[tid] = sig;
    out_cls[tid] = sig;
}

// ---------------- block branches: bf16 MFMA ----------------

__global__ __launch_bounds__(512, 2) void k_first(const float* __restrict__ x,
                                                  const unsigned short* __restrict__ wpk,
                                                  const float* __restrict__ bl,
                                                  const float* __restrict__ bc,
                                                  const float* __restrict__ clsv,
                                                  int b0, __hip_bfloat16* __restrict__ t1) {
    extern __shared__ unsigned short sh[];
    unsigned short* A = sh;                 // 1024*40
    unsigned short* halo = sh + 1024 * 40;  // 3*1156
    int bL = blockIdx.x, b = b0 + bL;
    bool cx = clsv[b] > 0.5f;
    int bh = b / NW, bw = b - bh * NW;
    int tid = threadIdx.x;
    for (int i = tid; i < 3 * 1156; i += 512) {
        int ci = i / 1156, rem = i - ci * 1156;
        int ry = rem / 34, rx = rem - ry * 34;
        int yg = bh * 20 + ry - 7, xg = bw * 20 + rx - 7;
        float v = ((unsigned)yg < (unsigned)H && (unsigned)xg < (unsigned)W)
                      ? x[ci * HW + yg * W + xg] : 0.f;
        halo[i] = f2bfu(v);
    }
    __syncthreads();
    for (int v = tid; v < 1024 * 32; v += 512) {
        int p = v >> 5, k = v & 31;
        unsigned short val = 0;
        if (k < 27) {
            int ci = k / 9, t = k - ci * 9;
            int dy = t / 3, dx = t - dy * 3;
            int y = p >> 5, xx = p & 31;
            val = halo[ci * 1156 + (y + dy) * 34 + (xx + dx)];
        }
        A[p * 40 + k] = val;
    }
    __syncthreads();
    int lane = tid & 63, wave = tid >> 6;
    int col = lane & 15, kq = lane >> 4;
    const unsigned short* wf = wpk + (cx ? WPK_F_CX : WPK_F_LT);
    const float* bi = cx ? bc : bl;
    int nT = cx ? 4 : 1;
    __hip_bfloat16* outb = t1 + (long)bL * 65536;
    for (int nt = 0; nt < nT; ++nt) {
        int co = nt * 16 + col;
        short8 Bf = *(const short8*)(wf + co * 32 + kq * 8);
        float bv = bi[co];
#pragma unroll 1
        for (int i = 0; i < 8; ++i) {
            int mt = wave * 8 + i;
            short8 a = *(const short8*)(A + (mt * 16 + col) * 40 + kq * 8);
            f32x4 acc = {bv, bv, bv, bv};
            acc = __builtin_amdgcn_mfma_f32_16x16x32_bf16(a, Bf, acc, 0, 0, 0);
            int prow = mt * 16 + kq * 4;
#pragma unroll
            for (int r = 0; r < 4; ++r)
                outb[(prow + r) * 64 + co] = __float2bfloat16(fmaxf(acc[r], 0.f));
        }
    }
}

// taps-outer conv over one 32x32 block from XOR-swizzled LDS.
template <int CINP, int NT, int GOUT, bool RELU>
__device__ __forceinline__ void conv_mfma(const unsigned short* __restrict__ sh,
                                          const unsigned short* __restrict__ wpk,
                                          const float* __restrict__ bias,
                                          unsigned short* __restrict__ outg, int tid) {
    constexpr int KC = CINP / 32;
    int lane = tid & 63, wave = tid >> 6;
    int col = lane & 15, kq = lane >> 4;
    f32x4 acc[8][NT];
#pragma unroll
    for (int nt = 0; nt < NT; ++nt) {
        float bv = bias[nt * 16 + col];
#pragma unroll
        for (int i = 0; i < 8; ++i) acc[i][nt] = f32x4{bv, bv, bv, bv};
    }
#pragma unroll 1
    for (int t = 0; t < 9; ++t) {
        int dy = t / 3, dx = t - dy * 3;
        short8 B[NT][KC];
#pragma unroll
        for (int nt = 0; nt < NT; ++nt)
#pragma unroll
            for (int kc = 0; kc < KC; ++kc)
                B[nt][kc] = *(const short8*)(wpk + ((nt * 16 + col) * 9 + t) * CINP +
                                             kc * 32 + kq * 8);
#pragma unroll
        for (int i = 0; i < 8; ++i) {
            int mt = wave * 8 + i;
            int yp = (mt >> 1) + dy - 1;
            if ((unsigned)yp > 31u) continue;  // wave-uniform skip
            int xs = ((mt & 1) << 4) + col + dx - 1;
            bool xv = (unsigned)xs < 32u;
            int xc = xs < 0 ? 0 : (xs > 31 ? 31 : xs);
            int pr = yp * 32 + xc;
#pragma unroll
            for (int kc = 0; kc < KC; ++kc) {
                int c = kc * 4 + kq;
                int cs = (CINP == 64) ? (c ^ (pr & 7)) : (c ^ ((pr >> 1) & 3));
                short8 a = *(const short8*)(sh + pr * CINP + cs * 8);
                if (!xv) a = short8{0, 0, 0, 0, 0, 0, 0, 0};
#pragma unroll
                for (int nt = 0; nt < NT; ++nt)
                    acc[i][nt] = __builtin_amdgcn_mfma_f32_16x16x32_bf16(a, B[nt][kc],
                                                                         acc[i][nt], 0, 0, 0);
            }
        }
    }
#pragma unroll
    for (int i = 0; i < 8; ++i) {
        int prow = (wave * 8 + i) * 16 + kq * 4;
#pragma unroll
        for (int nt = 0; nt < NT; ++nt) {
            int co = nt * 16 + col;
#pragma unroll
            for (int r = 0; r < 4; ++r) {
                float v = acc[i][nt][r];
                if (RELU) v = fmaxf(v, 0.f);
                outg[(prow + r) * GOUT + co] = f2bfu(v);
            }
        }
    }
}

// merged second conv: cx blocks do 64->64 (t1->t2, relu); lt blocks do 16->48 (t1->t3).
__global__ __launch_bounds__(512, 2) void k_b2(const __hip_bfloat16* __restrict__ t1,
                                               const unsigned short* __restrict__ wpk,
                                               const float* __restrict__ cx_b2,
                                               const float* __restrict__ lt_b2,
                                               const float* __restrict__ clsv, int b0,
                                               __hip_bfloat16* __restrict__ t2,
                                               __hip_bfloat16* __restrict__ t3) {
    extern __shared__ unsigned short sh[];
    int bL = blockIdx.x;
    bool cx = clsv[b0 + bL] > 0.5f;
    int tid = threadIdx.x;
    const unsigned short* inb = (const unsigned short*)t1 + (long)bL * 65536;
    if (cx) {
        for (int u = tid; u < 8192; u += 512) {
            int p = u >> 3, c = u & 7;
            *(ushort8*)(sh + p * 64 + (c ^ (p & 7)) * 8) =
                *(const ushort8*)(inb + p * 64 + c * 8);
        }
        __syncthreads();
        conv_mfma<64, 4, 64, true>(sh, wpk + WPK_CX2, cx_b2,
                                   (unsigned short*)t2 + (long)bL * 65536, tid);
    } else {
        ushort8 z = {0, 0, 0, 0, 0, 0, 0, 0};
        for (int u = tid; u < 4096; u += 512) {
            int p = u >> 2, c = u & 3;
            ushort8 v = (c < 2) ? *(const ushort8*)(inb + p * 64 + c * 8) : z;
            *(ushort8*)(sh + p * 32 + (c ^ ((p >> 1) & 3)) * 8) = v;
        }
        __syncthreads();
        conv_mfma<32, 3, 48, false>(sh, wpk + WPK_LT2, lt_b2,
                                    (unsigned short*)t3 + (long)bL * 49152, tid);
    }
}

// third conv, cx only: 64->48 (t2->t3).
__global__ __launch_bounds__(512, 2) void k_b3(const __hip_bfloat16* __restrict__ t2,
                                               const unsigned short* __restrict__ wpk,
                                               const float* __restrict__ cx_b3,
                                               const float* __restrict__ clsv, int b0,
                                               __hip_bfloat16* __restrict__ t3) {
    extern __shared__ unsigned short sh[];
    int bL = blockIdx.x;
    if (!(clsv[b0 + bL] > 0.5f)) return;
    int tid = threadIdx.x;
    const unsigned short* inb = (const unsigned short*)t2 + (long)bL * 65536;
    for (int u = tid; u < 8192; u += 512) {
        int p = u >> 3, c = u & 7;
        *(ushort8*)(sh + p * 64 + (c ^ (p & 7)) * 8) = *(const ushort8*)(inb + p * 64 + c * 8);
    }
    __syncthreads();
    conv_mfma<64, 3, 48, false>(sh, wpk + WPK_CX3, cx_b3,
                                (unsigned short*)t3 + (long)bL * 49152, tid);
}

// pixel shuffle + clip + crop + reassemble from bf16 t3 [p][48]
__global__ __launch_bounds__(256) void k_assemble(const unsigned short* __restrict__ t3,
                                                  int b0, int nb, float* __restrict__ out) {
    int idx = blockIdx.x * 256 + threadIdx.x;
    if (idx >= nb * 19200) return;
    int bL = idx / 19200;
    int rem = idx - bL * 19200;
    int ch = rem / 6400;
    int rem2 = rem - ch * 6400;
    int r = rem2 / 80, s = rem2 - r * 80;
    int b = b0 + bL;
    int bh = b / NW, bw = b - bh * NW;
    int yy = r + 24, xx = s + 24;
    int pc = ch * 16 + (yy & 3) * 4 + (xx & 3);
    float v = bf2f(t3[(long)bL * 49152 + ((yy >> 2) * 32 + (xx >> 2)) * 48 + pc]);
    v = fminf(fmaxf(v, 0.f), 1.f);
    out[ch * (1920 * 1280) + (bh * 80 + r) * 1280 + (bw * 80 + s)] = v;
}

extern "C" void kernel_launch(void* const* d_in, const int* in_sizes, int n_in,
                              void* d_out, int out_size, void* d_ws, size_t ws_size,
                              hipStream_t stream) {
    const float* x      = (const float*)d_in[0];
    const float* cls_w1 = (const float*)d_in[1];
    const float* cls_b1 = (const float*)d_in[2];
    const float* cls_w2 = (const float*)d_in[3];
    const float* cls_b2 = (const float*)d_in[4];
    const float* cls_w3 = (const float*)d_in[5];
    const float* cls_b3 = (const float*)d_in[6];
    const float* cls_w4 = (const float*)d_in[7];
    const float* cls_b4 = (const float*)d_in[8];
    const float* cls_w5 = (const float*)d_in[9];
    const float* cls_b5 = (const float*)d_in[10];
    const float* lt_w1  = (const float*)d_in[11];
    const float* lt_b1  = (const float*)d_in[12];
    const float* lt_w2  = (const float*)d_in[13];
    const float* lt_b2  = (const float*)d_in[14];
    const float* cx_w1  = (const float*)d_in[15];
    const float* cx_b1  = (const float*)d_in[16];
    const float* cx_w2  = (const float*)d_in[17];
    const float* cx_b2  = (const float*)d_in[18];
    const float* cx_w3  = (const float*)d_in[19];
    const float* cx_b3  = (const float*)d_in[20];

    float* ws = (float*)d_ws;
    float* out = (float*)d_out;

    // persistent small buffers
    size_t off = 0;
    float* c2 = ws + off;   off += (size_t)32 * HW2;   // 1,228,800
    float* c4 = ws + off;   off += (size_t)8 * HW4;    //    76,800
    float* clsv = ws + off; off += 384;
    unsigned short* wpk = (unsigned short*)(ws + off); off += (WPK_TOT + 1) / 2;
    size_t fixed = off;

    // scratch region: p3 (classifier phase), then t1/t2/t3 (block phase, aliases p3).
    float* p3 = ws + fixed;                      // 32*HW2 fl
    long avail_bytes = (long)ws_size - (long)fixed * 4;
    long per_block_bytes = (65536 + 65536 + 49152) * 2;  // 360448
    long cmax = avail_bytes / per_block_bytes;
    int chunk = (int)(cmax < 1 ? 1 : (cmax > NB ? NB : cmax));
    __hip_bfloat16* t1 = (__hip_bfloat16*)(ws + fixed);
    __hip_bfloat16* t2 = t1 + (long)chunk * 65536;
    __hip_bfloat16* t3 = t2 + (long)chunk * 65536;

    (void)hipFuncSetAttribute((const void*)k_first,
                              hipFuncAttributeMaxDynamicSharedMemorySize, 88856);
    (void)hipFuncSetAttribute((const void*)k_b2,
                              hipFuncAttributeMaxDynamicSharedMemorySize, 131072);
    (void)hipFuncSetAttribute((const void*)k_b3,
                              hipFuncAttributeMaxDynamicSharedMemorySize, 131072);

    k_pack<<<(WPK_TOT + 255) / 256, 256, 0, stream>>>(cx_w2, cx_w3, lt_w2, cx_w1, lt_w1, wpk);
    k_cls12f<<<600, 256, 0, stream>>>(x, cls_w1, cls_b1, cls_w2, cls_b2, c2);
    k_cls3<<<dim3((HW2 + 255) / 256, 2), 256, 0, stream>>>(c2, cls_w3, cls_b3, p3);
    k_cls4f<<<150, 256, 0, stream>>>(p3, cls_w4, cls_b4, c4);
    k_cls5<<<1, 384, 0, stream>>>(c4, cls_w5, cls_b5, clsv, out + IMG_PIX);

    for (int b0 = 0; b0 < NB; b0 += chunk) {
        int n = chunk < (NB - b0) ? chunk : (NB - b0);
        k_first<<<n, 512, 88856, stream>>>(x, wpk, lt_b1, cx_b1, clsv, b0, t1);
        k_b2<<<n, 512, 131072, stream>>>(t1, wpk, cx_b2, lt_b2, clsv, b0, t2, t3);
        k_b3<<<n, 512, 131072, stream>>>(t2, wpk, cx_b3, clsv, b0, t3);
        k_assemble<<<(n * 19200 + 255) / 256, 256, 0, stream>>>(
            (const unsigned short*)t3, b0, n, out);
    }
}

// Round 7
// 320.016 us; speedup vs baseline: 1.1031x; 1.0074x over previous
//
#include <hip/hip_runtime.h>
#include <hip/hip_bf16.h>
#include <math.h>

static constexpr int H = 480, W = 320, NH = 24, NW = 16, NB = 384;
static constexpr int HW = H * W;            // 153600
static constexpr int H2 = 240, W2 = 160;
static constexpr int HW2 = H2 * W2;         // 38400
static constexpr int H4 = 120, W4 = 80;
static constexpr int HW4 = H4 * W4;         // 9600
static constexpr int IMG_PIX = 3 * 1920 * 1280;  // 7372800

typedef __attribute__((ext_vector_type(8))) short short8;
typedef __attribute__((ext_vector_type(4))) float f32x4;
typedef __attribute__((ext_vector_type(8))) unsigned short ushort8;

// packed-weight region offsets (ushort elements)
static constexpr int WPK_CX2 = 0;          // [64][9][64]
static constexpr int WPK_CX3 = 36864;      // [48][9][64]
static constexpr int WPK_LT2 = 64512;      // [48][9][32] (ci>=16 zero)
static constexpr int WPK_F_CX = 78336;     // [64][32] (k>=27 zero)
static constexpr int WPK_F_LT = 80384;     // [16][32]
static constexpr int WPK_TOT = 80896;

__device__ __forceinline__ int iclamp(int v, int lo, int hi) {
    return v < lo ? lo : (v > hi ? hi : v);
}
__device__ __forceinline__ unsigned short f2bfu(float x) {
    __hip_bfloat16 h = __float2bfloat16(x);
    return *reinterpret_cast<unsigned short*>(&h);
}
__device__ __forceinline__ float bf2f(unsigned short u) {
    __hip_bfloat16 h = *reinterpret_cast<__hip_bfloat16*>(&u);
    return __bfloat162float(h);
}

// ---------------- weight pre-pack ----------------

__global__ __launch_bounds__(256) void k_pack(const float* __restrict__ cx_w2,
                                              const float* __restrict__ cx_w3,
                                              const float* __restrict__ lt_w2,
                                              const float* __restrict__ cx_w1,
                                              const float* __restrict__ lt_w1,
                                              unsigned short* __restrict__ wpk) {
    int i = blockIdx.x * 256 + threadIdx.x;
    if (i >= WPK_TOT) return;
    float v = 0.f;
    if (i < WPK_CX3) {
        int co = i / 576, t = (i / 64) % 9, ci = i % 64;
        v = cx_w2[(co * 64 + ci) * 9 + t];
    } else if (i < WPK_LT2) {
        int j = i - WPK_CX3;
        int co = j / 576, t = (j / 64) % 9, ci = j % 64;
        v = cx_w3[(co * 64 + ci) * 9 + t];
    } else if (i < WPK_F_CX) {
        int j = i - WPK_LT2;
        int co = j / 288, t = (j / 32) % 9, ci = j % 32;
        v = (ci < 16) ? lt_w2[(co * 16 + ci) * 9 + t] : 0.f;
    } else if (i < WPK_F_LT) {
        int j = i - WPK_F_CX;
        int co = j >> 5, k = j & 31;
        v = (k < 27) ? cx_w1[co * 27 + k] : 0.f;
    } else {
        int j = i - WPK_F_LT;
        int co = j >> 5, k = j & 31;
        v = (k < 27) ? lt_w1[co * 27 + k] : 0.f;
    }
    wpk[i] = f2bfu(v);
}

// ---------------- classifier (fp32, exact) ----------------

__global__ __launch_bounds__(256) void k_cls1(const float* __restrict__ x,
                                              const float* __restrict__ w,
                                              const float* __restrict__ b,
                                              float* __restrict__ out) {
    int p = blockIdx.x * 256 + threadIdx.x;
    if (p >= HW) return;
    int y = p / W, xx = p - y * W;
    float in[3][9];
#pragma unroll
    for (int ci = 0; ci < 3; ++ci)
#pragma unroll
        for (int dy = 0; dy < 3; ++dy) {
            int yy = iclamp(y + dy - 1, 0, H - 1);
#pragma unroll
            for (int dx = 0; dx < 3; ++dx) {
                int xc = iclamp(xx + dx - 1, 0, W - 1);
                in[ci][dy * 3 + dx] = x[ci * HW + yy * W + xc];
            }
        }
#pragma unroll
    for (int co = 0; co < 32; ++co) {
        float acc = b[co];
#pragma unroll
        for (int k = 0; k < 27; ++k) acc = fmaf(w[co * 27 + k], in[k / 9][k % 9], acc);
        out[co * HW + p] = fmaxf(acc, 0.f);
    }
}

// conv2(32->32 edge pad)+relu+2x2 maxpool; thread per PRE-pool pixel, co-split x2.
// grid (600, 2); wg = 16x16 pre-pool tile; pool via 16KB LDS.
__global__ __launch_bounds__(256, 4) void k_cls2p(const float* __restrict__ in,
                                                  const float* __restrict__ w,
                                                  const float* __restrict__ b,
                                                  float* __restrict__ out) {
    __shared__ float lds[16 * 256];
    int t = threadIdx.x;
    int tile = blockIdx.x;           // 30 x 20 tiles
    int coc = blockIdx.y;            // 0..1
    int ty = tile / 20, tx = tile - ty * 20;
    int ly = t >> 4, lx = t & 15;
    int y = ty * 16 + ly, xx = tx * 16 + lx;
    float acc[16];
#pragma unroll
    for (int co = 0; co < 16; ++co) acc[co] = b[coc * 16 + co];
    for (int ci = 0; ci < 32; ++ci) {
        float v[9];
#pragma unroll
        for (int dy = 0; dy < 3; ++dy) {
            int yy = iclamp(y + dy - 1, 0, H - 1);
#pragma unroll
            for (int dx = 0; dx < 3; ++dx) {
                int xc = iclamp(xx + dx - 1, 0, W - 1);
                v[dy * 3 + dx] = in[ci * HW + yy * W + xc];
            }
        }
#pragma unroll
        for (int co = 0; co < 16; ++co) {
            const float* wp = w + (coc * 16 + co) * 288 + ci * 9;
#pragma unroll
            for (int k = 0; k < 9; ++k) acc[co] = fmaf(wp[k], v[k], acc[co]);
        }
    }
#pragma unroll
    for (int co = 0; co < 16; ++co) lds[co * 256 + t] = fmaxf(acc[co], 0.f);
    __syncthreads();
    // 16co x 64 pooled outputs per wg -> 4 per thread
#pragma unroll
    for (int k = 0; k < 4; ++k) {
        int o = t + k * 256;
        int co = o >> 6, rem = o & 63;
        int py = rem >> 3, px = rem & 7;
        const float* lp = lds + co * 256 + py * 32 + px * 2;
        float m = fmaxf(fmaxf(lp[0], lp[1]), fmaxf(lp[16], lp[17]));
        out[(coc * 16 + co) * HW2 + (ty * 8 + py) * W2 + tx * 8 + px] = m;
    }
}

// conv3 32->16 edge pad at 240x160, ci-split x2, fp32 partials (no relu).
__global__ __launch_bounds__(256, 4) void k_cls3(const float* __restrict__ in,
                                                 const float* __restrict__ w,
                                                 const float* __restrict__ b,
                                                 float* __restrict__ p3) {
    int p = blockIdx.x * 256 + threadIdx.x;
    if (p >= HW2) return;
    int s = blockIdx.y;  // 0..1
    int y = p / W2, xx = p - y * W2;
    float acc[16];
#pragma unroll
    for (int co = 0; co < 16; ++co) acc[co] = s ? 0.f : b[co];
    for (int cil = 0; cil < 16; ++cil) {
        int ci = s * 16 + cil;
        float v[9];
#pragma unroll
        for (int dy = 0; dy < 3; ++dy) {
            int yy = iclamp(y + dy - 1, 0, H2 - 1);
#pragma unroll
            for (int dx = 0; dx < 3; ++dx) {
                int xc = iclamp(xx + dx - 1, 0, W2 - 1);
                v[dy * 3 + dx] = in[ci * HW2 + yy * W2 + xc];
            }
        }
#pragma unroll
        for (int co = 0; co < 16; ++co)
#pragma unroll
            for (int k = 0; k < 9; ++k)
                acc[co] = fmaf(w[co * 288 + ci * 9 + k], v[k], acc[co]);
    }
#pragma unroll
    for (int co = 0; co < 16; ++co) p3[(s * 16 + co) * HW2 + p] = acc[co];
}

// fused (partial-sum + relu) -> conv4(16->8, edge pad) + relu + 2x2 maxpool.
__global__ __launch_bounds__(256, 4) void k_cls4f(const float* __restrict__ p3,
                                                  const float* __restrict__ w,
                                                  const float* __restrict__ b,
                                                  float* __restrict__ out) {
    __shared__ float lds[8 * 256];
    int t = threadIdx.x;
    int tile = blockIdx.x;           // 15 x 10 tiles
    int ty = tile / 10, tx = tile - ty * 10;
    int ly = t >> 4, lx = t & 15;
    int y = ty * 16 + ly, xx = tx * 16 + lx;
    float acc[8];
#pragma unroll
    for (int co = 0; co < 8; ++co) acc[co] = b[co];
    for (int ci = 0; ci < 16; ++ci) {
        float v[9];
#pragma unroll
        for (int dy = 0; dy < 3; ++dy) {
            int yy = iclamp(y + dy - 1, 0, H2 - 1);
#pragma unroll
            for (int dx = 0; dx < 3; ++dx) {
                int xc = iclamp(xx + dx - 1, 0, W2 - 1);
                int idx = ci * HW2 + yy * W2 + xc;
                v[dy * 3 + dx] = fmaxf(p3[idx] + p3[idx + 16 * HW2], 0.f);
            }
        }
#pragma unroll
        for (int co = 0; co < 8; ++co) {
            const float* wp = w + co * 144 + ci * 9;
#pragma unroll
            for (int k = 0; k < 9; ++k) acc[co] = fmaf(wp[k], v[k], acc[co]);
        }
    }
#pragma unroll
    for (int co = 0; co < 8; ++co) lds[co * 256 + t] = fmaxf(acc[co], 0.f);
    __syncthreads();
#pragma unroll
    for (int k = 0; k < 2; ++k) {
        int o = t + k * 256;
        int co = o >> 6, rem = o & 63;
        int py = rem >> 3, px = rem & 7;
        const float* lp = lds + co * 256 + py * 32 + px * 2;
        float m = fmaxf(fmaxf(lp[0], lp[1]), fmaxf(lp[16], lp[17]));
        out[co * HW4 + (ty * 8 + py) * W4 + tx * 8 + px] = m;
    }
}

__global__ __launch_bounds__(384) void k_cls5(const float* __restrict__ in,
                                              const float* __restrict__ w,
                                              const float* __restrict__ b,
                                              float* __restrict__ clsv,
                                              float* __restrict__ out_cls) {
    int tid = threadIdx.x;
    if (tid >= NB) return;
    int oy = tid / NW, ox = tid - oy * NW;
    float s = b[0];
    for (int ci = 0; ci < 8; ++ci)
#pragma unroll
        for (int ky = 0; ky < 5; ++ky)
#pragma unroll
            for (int kx = 0; kx < 5; ++kx)
                s = fmaf(w[ci * 25 + ky * 5 + kx],
                         in[ci * HW4 + (oy * 5 + ky) * W4 + (ox * 5 + kx)], s);
    float sig = 1.f / (1.f + expf(-s));
    clsv[tid] = sig;
    out_cls[tid] = sig;
}

// ---------------- block branches: bf16 MFMA ----------------

__global__ __launch_bounds__(512, 2) void k_first(const float* __restrict__ x,
                                                  const unsigned short* __restrict__ wpk,
                                                  const float* __restrict__ bl,
                                                  const float* __restrict__ bc,
                                                  const float* __restrict__ clsv,
                                                  int b0, __hip_bfloat16* __restrict__ t1) {
    extern __shared__ unsigned short sh[];
    unsigned short* A = sh;                 // 1024*40
    unsigned short* halo = sh + 1024 * 40;  // 3*1156
    int bL = blockIdx.x, b = b0 + bL;
    bool cx = clsv[b] > 0.5f;
    int bh = b / NW, bw = b - bh * NW;
    int tid = threadIdx.x;
    for (int i = tid; i < 3 * 1156; i += 512) {
        int ci = i / 1156, rem = i - ci * 1156;
        int ry = rem / 34, rx = rem - ry * 34;
        int yg = bh * 20 + ry - 7, xg = bw * 20 + rx - 7;
        float v = ((unsigned)yg < (unsigned)H && (unsigned)xg < (unsigned)W)
                      ? x[ci * HW + yg * W + xg] : 0.f;
        halo[i] = f2bfu(v);
    }
    __syncthreads();
    for (int v = tid; v < 1024 * 32; v += 512) {
        int p = v >> 5, k = v & 31;
        unsigned short val = 0;
        if (k < 27) {
            int ci = k / 9, t = k - ci * 9;
            int dy = t / 3, dx = t - dy * 3;
            int y = p >> 5, xx = p & 31;
            val = halo[ci * 1156 + (y + dy) * 34 + (xx + dx)];
        }
        A[p * 40 + k] = val;
    }
    __syncthreads();
    int lane = tid & 63, wave = tid >> 6;
    int col = lane & 15, kq = lane >> 4;
    const unsigned short* wf = wpk + (cx ? WPK_F_CX : WPK_F_LT);
    const float* bi = cx ? bc : bl;
    int nT = cx ? 4 : 1;
    __hip_bfloat16* outb = t1 + (long)bL * 65536;
    for (int nt = 0; nt < nT; ++nt) {
        int co = nt * 16 + col;
        short8 Bf = *(const short8*)(wf + co * 32 + kq * 8);
        float bv = bi[co];
#pragma unroll 1
        for (int i = 0; i < 8; ++i) {
            int mt = wave * 8 + i;
            short8 a = *(const short8*)(A + (mt * 16 + col) * 40 + kq * 8);
            f32x4 acc = {bv, bv, bv, bv};
            acc = __builtin_amdgcn_mfma_f32_16x16x32_bf16(a, Bf, acc, 0, 0, 0);
            int prow = mt * 16 + kq * 4;
#pragma unroll
            for (int r = 0; r < 4; ++r)
                outb[(prow + r) * 64 + co] = __float2bfloat16(fmaxf(acc[r], 0.f));
        }
    }
}

// taps-outer conv over one 32x32 block from XOR-swizzled LDS.
template <int CINP, int NT, int GOUT, bool RELU>
__device__ __forceinline__ void conv_mfma(const unsigned short* __restrict__ sh,
                                          const unsigned short* __restrict__ wpk,
                                          const float* __restrict__ bias,
                                          unsigned short* __restrict__ outg, int tid) {
    constexpr int KC = CINP / 32;
    int lane = tid & 63, wave = tid >> 6;
    int col = lane & 15, kq = lane >> 4;
    f32x4 acc[8][NT];
#pragma unroll
    for (int nt = 0; nt < NT; ++nt) {
        float bv = bias[nt * 16 + col];
#pragma unroll
        for (int i = 0; i < 8; ++i) acc[i][nt] = f32x4{bv, bv, bv, bv};
    }
#pragma unroll 1
    for (int t = 0; t < 9; ++t) {
        int dy = t / 3, dx = t - dy * 3;
        short8 B[NT][KC];
#pragma unroll
        for (int nt = 0; nt < NT; ++nt)
#pragma unroll
            for (int kc = 0; kc < KC; ++kc)
                B[nt][kc] = *(const short8*)(wpk + ((nt * 16 + col) * 9 + t) * CINP +
                                             kc * 32 + kq * 8);
#pragma unroll
        for (int i = 0; i < 8; ++i) {
            int mt = wave * 8 + i;
            int yp = (mt >> 1) + dy - 1;
            if ((unsigned)yp > 31u) continue;  // wave-uniform skip
            int xs = ((mt & 1) << 4) + col + dx - 1;
            bool xv = (unsigned)xs < 32u;
            int xc = xs < 0 ? 0 : (xs > 31 ? 31 : xs);
            int pr = yp * 32 + xc;
#pragma unroll
            for (int kc = 0; kc < KC; ++kc) {
                int c = kc * 4 + kq;
                int cs = (CINP == 64) ? (c ^ (pr & 7)) : (c ^ ((pr >> 1) & 3));
                short8 a = *(const short8*)(sh + pr * CINP + cs * 8);
                if (!xv) a = short8{0, 0, 0, 0, 0, 0, 0, 0};
#pragma unroll
                for (int nt = 0; nt < NT; ++nt)
                    acc[i][nt] = __builtin_amdgcn_mfma_f32_16x16x32_bf16(a, B[nt][kc],
                                                                         acc[i][nt], 0, 0, 0);
            }
        }
    }
#pragma unroll
    for (int i = 0; i < 8; ++i) {
        int prow = (wave * 8 + i) * 16 + kq * 4;
#pragma unroll
        for (int nt = 0; nt < NT; ++nt) {
            int co = nt * 16 + col;
#pragma unroll
            for (int r = 0; r < 4; ++r) {
                float v = acc[i][nt][r];
                if (RELU) v = fmaxf(v, 0.f);
                outg[(prow + r) * GOUT + co] = f2bfu(v);
            }
        }
    }
}

// merged second conv: cx blocks do 64->64 (t1->t2, relu); lt blocks do 16->48 (t1->t3).
__global__ __launch_bounds__(512, 2) void k_b2(const __hip_bfloat16* __restrict__ t1,
                                               const unsigned short* __restrict__ wpk,
                                               const float* __restrict__ cx_b2,
                                               const float* __restrict__ lt_b2,
                                               const float* __restrict__ clsv, int b0,
                                               __hip_bfloat16* __restrict__ t2,
                                               __hip_bfloat16* __restrict__ t3) {
    extern __shared__ unsigned short sh[];
    int bL = blockIdx.x;
    bool cx = clsv[b0 + bL] > 0.5f;
    int tid = threadIdx.x;
    const unsigned short* inb = (const unsigned short*)t1 + (long)bL * 65536;
    if (cx) {
        for (int u = tid; u < 8192; u += 512) {
            int p = u >> 3, c = u & 7;
            *(ushort8*)(sh + p * 64 + (c ^ (p & 7)) * 8) =
                *(const ushort8*)(inb + p * 64 + c * 8);
        }
        __syncthreads();
        conv_mfma<64, 4, 64, true>(sh, wpk + WPK_CX2, cx_b2,
                                   (unsigned short*)t2 + (long)bL * 65536, tid);
    } else {
        ushort8 z = {0, 0, 0, 0, 0, 0, 0, 0};
        for (int u = tid; u < 4096; u += 512) {
            int p = u >> 2, c = u & 3;
            ushort8 v = (c < 2) ? *(const ushort8*)(inb + p * 64 + c * 8) : z;
            *(ushort8*)(sh + p * 32 + (c ^ ((p >> 1) & 3)) * 8) = v;
        }
        __syncthreads();
        conv_mfma<32, 3, 48, false>(sh, wpk + WPK_LT2, lt_b2,
                                    (unsigned short*)t3 + (long)bL * 49152, tid);
    }
}

// third conv, cx only: 64->48 (t2->t3).
__global__ __launch_bounds__(512, 2) void k_b3(const __hip_bfloat16* __restrict__ t2,
                                               const unsigned short* __restrict__ wpk,
                                               const float* __restrict__ cx_b3,
                                               const float* __restrict__ clsv, int b0,
                                               __hip_bfloat16* __restrict__ t3) {
    extern __shared__ unsigned short sh[];
    int bL = blockIdx.x;
    if (!(clsv[b0 + bL] > 0.5f)) return;
    int tid = threadIdx.x;
    const unsigned short* inb = (const unsigned short*)t2 + (long)bL * 65536;
    for (int u = tid; u < 8192; u += 512) {
        int p = u >> 3, c = u & 7;
        *(ushort8*)(sh + p * 64 + (c ^ (p & 7)) * 8) = *(const ushort8*)(inb + p * 64 + c * 8);
    }
    __syncthreads();
    conv_mfma<64, 3, 48, false>(sh, wpk + WPK_CX3, cx_b3,
                                (unsigned short*)t3 + (long)bL * 49152, tid);
}

// pixel shuffle + clip + crop + reassemble from bf16 t3 [p][48]
__global__ __launch_bounds__(256) void k_assemble(const unsigned short* __restrict__ t3,
                                                  int b0, int nb, float* __restrict__ out) {
    int idx = blockIdx.x * 256 + threadIdx.x;
    if (idx >= nb * 19200) return;
    int bL = idx / 19200;
    int rem = idx - bL * 19200;
    int ch = rem / 6400;
    int rem2 = rem - ch * 6400;
    int r = rem2 / 80, s = rem2 - r * 80;
    int b = b0 + bL;
    int bh = b / NW, bw = b - bh * NW;
    int yy = r + 24, xx = s + 24;
    int pc = ch * 16 + (yy & 3) * 4 + (xx & 3);
    float v = bf2f(t3[(long)bL * 49152 + ((yy >> 2) * 32 + (xx >> 2)) * 48 + pc]);
    v = fminf(fmaxf(v, 0.f), 1.f);
    out[ch * (1920 * 1280) + (bh * 80 + r) * 1280 + (bw * 80 + s)] = v;
}

extern "C" void kernel_launch(void* const* d_in, const int* in_sizes, int n_in,
                              void* d_out, int out_size, void* d_ws, size_t ws_size,
                              hipStream_t stream) {
    const float* x      = (const float*)d_in[0];
    const float* cls_w1 = (const float*)d_in[1];
    const float* cls_b1 = (const float*)d_in[2];
    const float* cls_w2 = (const float*)d_in[3];
    const float* cls_b2 = (const float*)d_in[4];
    const float* cls_w3 = (const float*)d_in[5];
    const float* cls_b3 = (const float*)d_in[6];
    const float* cls_w4 = (const float*)d_in[7];
    const float* cls_b4 = (const float*)d_in[8];
    const float* cls_w5 = (const float*)d_in[9];
    const float* cls_b5 = (const float*)d_in[10];
    const float* lt_w1  = (const float*)d_in[11];
    const float* lt_b1  = (const float*)d_in[12];
    const float* lt_w2  = (const float*)d_in[13];
    const float* lt_b2  = (const float*)d_in[14];
    const float* cx_w1  = (const float*)d_in[15];
    const float* cx_b1  = (const float*)d_in[16];
    const float* cx_w2  = (const float*)d_in[17];
    const float* cx_b2  = (const float*)d_in[18];
    const float* cx_w3  = (const float*)d_in[19];
    const float* cx_b3  = (const float*)d_in[20];

    float* ws = (float*)d_ws;
    float* out = (float*)d_out;

    // persistent small buffers
    size_t off = 0;
    float* c2 = ws + off;   off += (size_t)32 * HW2;   // 1,228,800
    float* c4 = ws + off;   off += (size_t)8 * HW4;    //    76,800
    float* clsv = ws + off; off += 384;
    unsigned short* wpk = (unsigned short*)(ws + off); off += (WPK_TOT + 1) / 2;
    size_t fixed = off;

    // scratch region: c1 (classifier phase), p3 (aliases c1 after it's dead),
    // then t1/t2/t3 (block phase, aliases both).
    float* c1 = ws + fixed;                      // 32*HW fl
    float* p3 = ws + fixed;                      // 32*HW2 fl (c1 dead when written)
    long avail_bytes = (long)ws_size - (long)fixed * 4;
    long per_block_bytes = (65536 + 65536 + 49152) * 2;  // 360448
    long cmax = avail_bytes / per_block_bytes;
    int chunk = (int)(cmax < 1 ? 1 : (cmax > NB ? NB : cmax));
    __hip_bfloat16* t1 = (__hip_bfloat16*)(ws + fixed);
    __hip_bfloat16* t2 = t1 + (long)chunk * 65536;
    __hip_bfloat16* t3 = t2 + (long)chunk * 65536;

    (void)hipFuncSetAttribute((const void*)k_first,
                              hipFuncAttributeMaxDynamicSharedMemorySize, 88856);
    (void)hipFuncSetAttribute((const void*)k_b2,
                              hipFuncAttributeMaxDynamicSharedMemorySize, 131072);
    (void)hipFuncSetAttribute((const void*)k_b3,
                              hipFuncAttributeMaxDynamicSharedMemorySize, 131072);

    k_pack<<<(WPK_TOT + 255) / 256, 256, 0, stream>>>(cx_w2, cx_w3, lt_w2, cx_w1, lt_w1, wpk);
    k_cls1<<<(HW + 255) / 256, 256, 0, stream>>>(x, cls_w1, cls_b1, c1);
    k_cls2p<<<dim3(600, 2), 256, 0, stream>>>(c1, cls_w2, cls_b2, c2);
    k_cls3<<<dim3((HW2 + 255) / 256, 2), 256, 0, stream>>>(c2, cls_w3, cls_b3, p3);
    k_cls4f<<<150, 256, 0, stream>>>(p3, cls_w4, cls_b4, c4);
    k_cls5<<<1, 384, 0, stream>>>(c4, cls_w5, cls_b5, clsv, out + IMG_PIX);

    for (int b0 = 0; b0 < NB; b0 += chunk) {
        int n = chunk < (NB - b0) ? chunk : (NB - b0);
        k_first<<<n, 512, 88856, stream>>>(x, wpk, lt_b1, cx_b1, clsv, b0, t1);
        k_b2<<<n, 512, 131072, stream>>>(t1, wpk, cx_b2, lt_b2, clsv, b0, t2, t3);
        k_b3<<<n, 512, 131072, stream>>>(t2, wpk, cx_b3, clsv, b0, t3);
        k_assemble<<<(n * 19200 + 255) / 256, 256, 0, stream>>>(
            (const unsigned short*)t3, b0, n, out);
    }
}

// Round 8
// 280.320 us; speedup vs baseline: 1.2594x; 1.1416x over previous
//
#include <hip/hip_runtime.h>
#include <hip/hip_bf16.h>
#include <math.h>

static constexpr int H = 480, W = 320, NH = 24, NW = 16, NB = 384;
static constexpr int HW = H * W;            // 153600
static constexpr int H2 = 240, W2 = 160;
static constexpr int HW2 = H2 * W2;         // 38400
static constexpr int H4 = 120, W4 = 80;
static constexpr int HW4 = H4 * W4;         // 9600
static constexpr int IMG_PIX = 3 * 1920 * 1280;  // 7372800

typedef __attribute__((ext_vector_type(8))) short short8;
typedef __attribute__((ext_vector_type(4))) float f32x4;
typedef __attribute__((ext_vector_type(8))) unsigned short ushort8;

// packed-weight region offsets (ushort elements)
static constexpr int WPK_CX2 = 0;          // [64][9][64]
static constexpr int WPK_CX3 = 36864;      // [48][9][64]
static constexpr int WPK_LT2 = 64512;      // [48][9][32] (ci>=16 zero)
static constexpr int WPK_F_CX = 78336;     // [64][32] (k>=27 zero)
static constexpr int WPK_F_LT = 80384;     // [16][32]
static constexpr int WPK_TOT = 80896;

__device__ __forceinline__ int iclamp(int v, int lo, int hi) {
    return v < lo ? lo : (v > hi ? hi : v);
}
__device__ __forceinline__ unsigned short f2bfu(float x) {
    __hip_bfloat16 h = __float2bfloat16(x);
    return *reinterpret_cast<unsigned short*>(&h);
}
__device__ __forceinline__ float bf2f(unsigned short u) {
    __hip_bfloat16 h = *reinterpret_cast<__hip_bfloat16*>(&u);
    return __bfloat162float(h);
}

// ---------------- weight pre-pack ----------------

__global__ __launch_bounds__(256) void k_pack(const float* __restrict__ cx_w2,
                                              const float* __restrict__ cx_w3,
                                              const float* __restrict__ lt_w2,
                                              const float* __restrict__ cx_w1,
                                              const float* __restrict__ lt_w1,
                                              unsigned short* __restrict__ wpk) {
    int i = blockIdx.x * 256 + threadIdx.x;
    if (i >= WPK_TOT) return;
    float v = 0.f;
    if (i < WPK_CX3) {
        int co = i / 576, t = (i / 64) % 9, ci = i % 64;
        v = cx_w2[(co * 64 + ci) * 9 + t];
    } else if (i < WPK_LT2) {
        int j = i - WPK_CX3;
        int co = j / 576, t = (j / 64) % 9, ci = j % 64;
        v = cx_w3[(co * 64 + ci) * 9 + t];
    } else if (i < WPK_F_CX) {
        int j = i - WPK_LT2;
        int co = j / 288, t = (j / 32) % 9, ci = j % 32;
        v = (ci < 16) ? lt_w2[(co * 16 + ci) * 9 + t] : 0.f;
    } else if (i < WPK_F_LT) {
        int j = i - WPK_F_CX;
        int co = j >> 5, k = j & 31;
        v = (k < 27) ? cx_w1[co * 27 + k] : 0.f;
    } else {
        int j = i - WPK_F_LT;
        int co = j >> 5, k = j & 31;
        v = (k < 27) ? lt_w1[co * 27 + k] : 0.f;
    }
    wpk[i] = f2bfu(v);
}

// ---------------- classifier (fp32, exact) ----------------

__global__ __launch_bounds__(256) void k_cls1(const float* __restrict__ x,
                                              const float* __restrict__ w,
                                              const float* __restrict__ b,
                                              float* __restrict__ out) {
    int p = blockIdx.x * 256 + threadIdx.x;
    if (p >= HW) return;
    int y = p / W, xx = p - y * W;
    float in[3][9];
#pragma unroll
    for (int ci = 0; ci < 3; ++ci)
#pragma unroll
        for (int dy = 0; dy < 3; ++dy) {
            int yy = iclamp(y + dy - 1, 0, H - 1);
#pragma unroll
            for (int dx = 0; dx < 3; ++dx) {
                int xc = iclamp(xx + dx - 1, 0, W - 1);
                in[ci][dy * 3 + dx] = x[ci * HW + yy * W + xc];
            }
        }
#pragma unroll
    for (int co = 0; co < 32; ++co) {
        float acc = b[co];
#pragma unroll
        for (int k = 0; k < 27; ++k) acc = fmaf(w[co * 27 + k], in[k / 9][k % 9], acc);
        out[co * HW + p] = fmaxf(acc, 0.f);
    }
}

// conv2(32->32 edge pad)+relu+2x2 maxpool; thread per PRE-pool pixel,
// co-split x4 (8 couts each, acc[8] -> no spill), fused pool via 8KB LDS.
// grid (600, 4) = 2400 wgs = 9600 waves.
__global__ __launch_bounds__(256) void k_cls2c(const float* __restrict__ in,
                                               const float* __restrict__ w,
                                               const float* __restrict__ b,
                                               float* __restrict__ out) {
    __shared__ float lds[8 * 256];
    int t = threadIdx.x;
    int tile = blockIdx.x;           // 30 x 20 tiles of 16x16
    int coc = blockIdx.y;            // 0..3
    int ty = tile / 20, tx = tile - ty * 20;
    int ly = t >> 4, lx = t & 15;
    int y = ty * 16 + ly, xx = tx * 16 + lx;
    float acc[8];
#pragma unroll
    for (int co = 0; co < 8; ++co) acc[co] = b[coc * 8 + co];
    for (int ci = 0; ci < 32; ++ci) {
        float v[9];
#pragma unroll
        for (int dy = 0; dy < 3; ++dy) {
            int yy = iclamp(y + dy - 1, 0, H - 1);
#pragma unroll
            for (int dx = 0; dx < 3; ++dx) {
                int xc = iclamp(xx + dx - 1, 0, W - 1);
                v[dy * 3 + dx] = in[ci * HW + yy * W + xc];
            }
        }
#pragma unroll
        for (int co = 0; co < 8; ++co) {
            const float* wp = w + (coc * 8 + co) * 288 + ci * 9;
#pragma unroll
            for (int k = 0; k < 9; ++k) acc[co] = fmaf(wp[k], v[k], acc[co]);
        }
    }
#pragma unroll
    for (int co = 0; co < 8; ++co) lds[co * 256 + t] = fmaxf(acc[co], 0.f);
    __syncthreads();
    // 8co x 64 pooled outputs per wg -> 2 per thread
#pragma unroll
    for (int k = 0; k < 2; ++k) {
        int o = t + k * 256;
        int co = o >> 6, rem = o & 63;
        int py = rem >> 3, px = rem & 7;
        const float* lp = lds + co * 256 + py * 32 + px * 2;
        float m = fmaxf(fmaxf(lp[0], lp[1]), fmaxf(lp[16], lp[17]));
        out[(coc * 8 + co) * HW2 + (ty * 8 + py) * W2 + tx * 8 + px] = m;
    }
}

// conv3 32->16 edge pad at 240x160; co-split x2 (8 couts) x ci-split x2 (fp32
// partials, same split as prior rounds). grid (150, 2, 2) = 600 wgs.
__global__ __launch_bounds__(256) void k_cls3(const float* __restrict__ in,
                                              const float* __restrict__ w,
                                              const float* __restrict__ b,
                                              float* __restrict__ p3) {
    int p = blockIdx.x * 256 + threadIdx.x;
    if (p >= HW2) return;
    int cc = blockIdx.y;  // co chunk 0..1
    int s = blockIdx.z;   // ci half 0..1
    int y = p / W2, xx = p - y * W2;
    float acc[8];
#pragma unroll
    for (int co = 0; co < 8; ++co) acc[co] = s ? 0.f : b[cc * 8 + co];
    for (int cil = 0; cil < 16; ++cil) {
        int ci = s * 16 + cil;
        float v[9];
#pragma unroll
        for (int dy = 0; dy < 3; ++dy) {
            int yy = iclamp(y + dy - 1, 0, H2 - 1);
#pragma unroll
            for (int dx = 0; dx < 3; ++dx) {
                int xc = iclamp(xx + dx - 1, 0, W2 - 1);
                v[dy * 3 + dx] = in[ci * HW2 + yy * W2 + xc];
            }
        }
#pragma unroll
        for (int co = 0; co < 8; ++co)
#pragma unroll
            for (int k = 0; k < 9; ++k)
                acc[co] = fmaf(w[(cc * 8 + co) * 288 + ci * 9 + k], v[k], acc[co]);
    }
#pragma unroll
    for (int co = 0; co < 8; ++co) p3[(s * 16 + cc * 8 + co) * HW2 + p] = acc[co];
}

// fused (partial-sum + relu) -> conv4(16->8, edge pad) + relu + 2x2 maxpool.
__global__ __launch_bounds__(256) void k_cls4f(const float* __restrict__ p3,
                                               const float* __restrict__ w,
                                               const float* __restrict__ b,
                                               float* __restrict__ out) {
    __shared__ float lds[8 * 256];
    int t = threadIdx.x;
    int tile = blockIdx.x;           // 15 x 10 tiles
    int ty = tile / 10, tx = tile - ty * 10;
    int ly = t >> 4, lx = t & 15;
    int y = ty * 16 + ly, xx = tx * 16 + lx;
    float acc[8];
#pragma unroll
    for (int co = 0; co < 8; ++co) acc[co] = b[co];
    for (int ci = 0; ci < 16; ++ci) {
        float v[9];
#pragma unroll
        for (int dy = 0; dy < 3; ++dy) {
            int yy = iclamp(y + dy - 1, 0, H2 - 1);
#pragma unroll
            for (int dx = 0; dx < 3; ++dx) {
                int xc = iclamp(xx + dx - 1, 0, W2 - 1);
                int idx = ci * HW2 + yy * W2 + xc;
                v[dy * 3 + dx] = fmaxf(p3[idx] + p3[idx + 16 * HW2], 0.f);
            }
        }
#pragma unroll
        for (int co = 0; co < 8; ++co) {
            const float* wp = w + co * 144 + ci * 9;
#pragma unroll
            for (int k = 0; k < 9; ++k) acc[co] = fmaf(wp[k], v[k], acc[co]);
        }
    }
#pragma unroll
    for (int co = 0; co < 8; ++co) lds[co * 256 + t] = fmaxf(acc[co], 0.f);
    __syncthreads();
#pragma unroll
    for (int k = 0; k < 2; ++k) {
        int o = t + k * 256;
        int co = o >> 6, rem = o & 63;
        int py = rem >> 3, px = rem & 7;
        const float* lp = lds + co * 256 + py * 32 + px * 2;
        float m = fmaxf(fmaxf(lp[0], lp[1]), fmaxf(lp[16], lp[17]));
        out[co * HW4 + (ty * 8 + py) * W4 + tx * 8 + px] = m;
    }
}

__global__ __launch_bounds__(384) void k_cls5(const float* __restrict__ in,
                                              const float* __restrict__ w,
                                              const float* __restrict__ b,
                                              float* __restrict__ clsv,
                                              float* __restrict__ out_cls) {
    int tid = threadIdx.x;
    if (tid >= NB) return;
    int oy = tid / NW, ox = tid - oy * NW;
    float s = b[0];
    for (int ci = 0; ci < 8; ++ci)
#pragma unroll
        for (int ky = 0; ky < 5; ++ky)
#pragma unroll
            for (int kx = 0; kx < 5; ++kx)
                s = fmaf(w[ci * 25 + ky * 5 + kx],
                         in[ci * HW4 + (oy * 5 + ky) * W4 + (ox * 5 + kx)], s);
    float sig = 1.f / (1.f + expf(-s));
    clsv[tid] = sig;
    out_cls[tid] = sig;
}

// ---------------- block branches: bf16 MFMA ----------------

__global__ __launch_bounds__(512, 2) void k_first(const float* __restrict__ x,
                                                  const unsigned short* __restrict__ wpk,
                                                  const float* __restrict__ bl,
                                                  const float* __restrict__ bc,
                                                  const float* __restrict__ clsv,
                                                  int b0, __hip_bfloat16* __restrict__ t1) {
    extern __shared__ unsigned short sh[];
    unsigned short* A = sh;                 // 1024*40
    unsigned short* halo = sh + 1024 * 40;  // 3*1156
    int bL = blockIdx.x, b = b0 + bL;
    bool cx = clsv[b] > 0.5f;
    int bh = b / NW, bw = b - bh * NW;
    int tid = threadIdx.x;
    for (int i = tid; i < 3 * 1156; i += 512) {
        int ci = i / 1156, rem = i - ci * 1156;
        int ry = rem / 34, rx = rem - ry * 34;
        int yg = bh * 20 + ry - 7, xg = bw * 20 + rx - 7;
        float v = ((unsigned)yg < (unsigned)H && (unsigned)xg < (unsigned)W)
                      ? x[ci * HW + yg * W + xg] : 0.f;
        halo[i] = f2bfu(v);
    }
    __syncthreads();
    for (int v = tid; v < 1024 * 32; v += 512) {
        int p = v >> 5, k = v & 31;
        unsigned short val = 0;
        if (k < 27) {
            int ci = k / 9, t = k - ci * 9;
            int dy = t / 3, dx = t - dy * 3;
            int y = p >> 5, xx = p & 31;
            val = halo[ci * 1156 + (y + dy) * 34 + (xx + dx)];
        }
        A[p * 40 + k] = val;
    }
    __syncthreads();
    int lane = tid & 63, wave = tid >> 6;
    int col = lane & 15, kq = lane >> 4;
    const unsigned short* wf = wpk + (cx ? WPK_F_CX : WPK_F_LT);
    const float* bi = cx ? bc : bl;
    int nT = cx ? 4 : 1;
    __hip_bfloat16* outb = t1 + (long)bL * 65536;
    for (int nt = 0; nt < nT; ++nt) {
        int co = nt * 16 + col;
        short8 Bf = *(const short8*)(wf + co * 32 + kq * 8);
        float bv = bi[co];
#pragma unroll 1
        for (int i = 0; i < 8; ++i) {
            int mt = wave * 8 + i;
            short8 a = *(const short8*)(A + (mt * 16 + col) * 40 + kq * 8);
            f32x4 acc = {bv, bv, bv, bv};
            acc = __builtin_amdgcn_mfma_f32_16x16x32_bf16(a, Bf, acc, 0, 0, 0);
            int prow = mt * 16 + kq * 4;
#pragma unroll
            for (int r = 0; r < 4; ++r)
                outb[(prow + r) * 64 + co] = __float2bfloat16(fmaxf(acc[r], 0.f));
        }
    }
}

// taps-outer conv over one 32x32 block from XOR-swizzled LDS.
template <int CINP, int NT, int GOUT, bool RELU>
__device__ __forceinline__ void conv_mfma(const unsigned short* __restrict__ sh,
                                          const unsigned short* __restrict__ wpk,
                                          const float* __restrict__ bias,
                                          unsigned short* __restrict__ outg, int tid) {
    constexpr int KC = CINP / 32;
    int lane = tid & 63, wave = tid >> 6;
    int col = lane & 15, kq = lane >> 4;
    f32x4 acc[8][NT];
#pragma unroll
    for (int nt = 0; nt < NT; ++nt) {
        float bv = bias[nt * 16 + col];
#pragma unroll
        for (int i = 0; i < 8; ++i) acc[i][nt] = f32x4{bv, bv, bv, bv};
    }
#pragma unroll 1
    for (int t = 0; t < 9; ++t) {
        int dy = t / 3, dx = t - dy * 3;
        short8 B[NT][KC];
#pragma unroll
        for (int nt = 0; nt < NT; ++nt)
#pragma unroll
            for (int kc = 0; kc < KC; ++kc)
                B[nt][kc] = *(const short8*)(wpk + ((nt * 16 + col) * 9 + t) * CINP +
                                             kc * 32 + kq * 8);
#pragma unroll
        for (int i = 0; i < 8; ++i) {
            int mt = wave * 8 + i;
            int yp = (mt >> 1) + dy - 1;
            if ((unsigned)yp > 31u) continue;  // wave-uniform skip
            int xs = ((mt & 1) << 4) + col + dx - 1;
            bool xv = (unsigned)xs < 32u;
            int xc = xs < 0 ? 0 : (xs > 31 ? 31 : xs);
            int pr = yp * 32 + xc;
#pragma unroll
            for (int kc = 0; kc < KC; ++kc) {
                int c = kc * 4 + kq;
                int cs = (CINP == 64) ? (c ^ (pr & 7)) : (c ^ ((pr >> 1) & 3));
                short8 a = *(const short8*)(sh + pr * CINP + cs * 8);
                if (!xv) a = short8{0, 0, 0, 0, 0, 0, 0, 0};
#pragma unroll
                for (int nt = 0; nt < NT; ++nt)
                    acc[i][nt] = __builtin_amdgcn_mfma_f32_16x16x32_bf16(a, B[nt][kc],
                                                                         acc[i][nt], 0, 0, 0);
            }
        }
    }
#pragma unroll
    for (int i = 0; i < 8; ++i) {
        int prow = (wave * 8 + i) * 16 + kq * 4;
#pragma unroll
        for (int nt = 0; nt < NT; ++nt) {
            int co = nt * 16 + col;
#pragma unroll
            for (int r = 0; r < 4; ++r) {
                float v = acc[i][nt][r];
                if (RELU) v = fmaxf(v, 0.f);
                outg[(prow + r) * GOUT + co] = f2bfu(v);
            }
        }
    }
}

// merged second conv: cx blocks do 64->64 (t1->t2, relu); lt blocks do 16->48 (t1->t3).
__global__ __launch_bounds__(512, 2) void k_b2(const __hip_bfloat16* __restrict__ t1,
                                               const unsigned short* __restrict__ wpk,
                                               const float* __restrict__ cx_b2,
                                               const float* __restrict__ lt_b2,
                                               const float* __restrict__ clsv, int b0,
                                               __hip_bfloat16* __restrict__ t2,
                                               __hip_bfloat16* __restrict__ t3) {
    extern __shared__ unsigned short sh[];
    int bL = blockIdx.x;
    bool cx = clsv[b0 + bL] > 0.5f;
    int tid = threadIdx.x;
    const unsigned short* inb = (const unsigned short*)t1 + (long)bL * 65536;
    if (cx) {
        for (int u = tid; u < 8192; u += 512) {
            int p = u >> 3, c = u & 7;
            *(ushort8*)(sh + p * 64 + (c ^ (p & 7)) * 8) =
                *(const ushort8*)(inb + p * 64 + c * 8);
        }
        __syncthreads();
        conv_mfma<64, 4, 64, true>(sh, wpk + WPK_CX2, cx_b2,
                                   (unsigned short*)t2 + (long)bL * 65536, tid);
    } else {
        ushort8 z = {0, 0, 0, 0, 0, 0, 0, 0};
        for (int u = tid; u < 4096; u += 512) {
            int p = u >> 2, c = u & 3;
            ushort8 v = (c < 2) ? *(const ushort8*)(inb + p * 64 + c * 8) : z;
            *(ushort8*)(sh + p * 32 + (c ^ ((p >> 1) & 3)) * 8) = v;
        }
        __syncthreads();
        conv_mfma<32, 3, 48, false>(sh, wpk + WPK_LT2, lt_b2,
                                    (unsigned short*)t3 + (long)bL * 49152, tid);
    }
}

// third conv, cx only: 64->48 (t2->t3).
__global__ __launch_bounds__(512, 2) void k_b3(const __hip_bfloat16* __restrict__ t2,
                                               const unsigned short* __restrict__ wpk,
                                               const float* __restrict__ cx_b3,
                                               const float* __restrict__ clsv, int b0,
                                               __hip_bfloat16* __restrict__ t3) {
    extern __shared__ unsigned short sh[];
    int bL = blockIdx.x;
    if (!(clsv[b0 + bL] > 0.5f)) return;
    int tid = threadIdx.x;
    const unsigned short* inb = (const unsigned short*)t2 + (long)bL * 65536;
    for (int u = tid; u < 8192; u += 512) {
        int p = u >> 3, c = u & 7;
        *(ushort8*)(sh + p * 64 + (c ^ (p & 7)) * 8) = *(const ushort8*)(inb + p * 64 + c * 8);
    }
    __syncthreads();
    conv_mfma<64, 3, 48, false>(sh, wpk + WPK_CX3, cx_b3,
                                (unsigned short*)t3 + (long)bL * 49152, tid);
}

// pixel shuffle + clip + crop + reassemble from bf16 t3 [p][48]
__global__ __launch_bounds__(256) void k_assemble(const unsigned short* __restrict__ t3,
                                                  int b0, int nb, float* __restrict__ out) {
    int idx = blockIdx.x * 256 + threadIdx.x;
    if (idx >= nb * 19200) return;
    int bL = idx / 19200;
    int rem = idx - bL * 19200;
    int ch = rem / 6400;
    int rem2 = rem - ch * 6400;
    int r = rem2 / 80, s = rem2 - r * 80;
    int b = b0 + bL;
    int bh = b / NW, bw = b - bh * NW;
    int yy = r + 24, xx = s + 24;
    int pc = ch * 16 + (yy & 3) * 4 + (xx & 3);
    float v = bf2f(t3[(long)bL * 49152 + ((yy >> 2) * 32 + (xx >> 2)) * 48 + pc]);
    v = fminf(fmaxf(v, 0.f), 1.f);
    out[ch * (1920 * 1280) + (bh * 80 + r) * 1280 + (bw * 80 + s)] = v;
}

extern "C" void kernel_launch(void* const* d_in, const int* in_sizes, int n_in,
                              void* d_out, int out_size, void* d_ws, size_t ws_size,
                              hipStream_t stream) {
    const float* x      = (const float*)d_in[0];
    const float* cls_w1 = (const float*)d_in[1];
    const float* cls_b1 = (const float*)d_in[2];
    const float* cls_w2 = (const float*)d_in[3];
    const float* cls_b2 = (const float*)d_in[4];
    const float* cls_w3 = (const float*)d_in[5];
    const float* cls_b3 = (const float*)d_in[6];
    const float* cls_w4 = (const float*)d_in[7];
    const float* cls_b4 = (const float*)d_in[8];
    const float* cls_w5 = (const float*)d_in[9];
    const float* cls_b5 = (const float*)d_in[10];
    const float* lt_w1  = (const float*)d_in[11];
    const float* lt_b1  = (const float*)d_in[12];
    const float* lt_w2  = (const float*)d_in[13];
    const float* lt_b2  = (const float*)d_in[14];
    const float* cx_w1  = (const float*)d_in[15];
    const float* cx_b1  = (const float*)d_in[16];
    const float* cx_w2  = (const float*)d_in[17];
    const float* cx_b2  = (const float*)d_in[18];
    const float* cx_w3  = (const float*)d_in[19];
    const float* cx_b3  = (const float*)d_in[20];

    float* ws = (float*)d_ws;
    float* out = (float*)d_out;

    // persistent small buffers
    size_t off = 0;
    float* c2 = ws + off;   off += (size_t)32 * HW2;   // 1,228,800
    float* c4 = ws + off;   off += (size_t)8 * HW4;    //    76,800
    float* clsv = ws + off; off += 384;
    unsigned short* wpk = (unsigned short*)(ws + off); off += (WPK_TOT + 1) / 2;
    size_t fixed = off;

    // scratch region: c1 (classifier phase), p3 (aliases c1 after it's dead),
    // then t1/t2/t3 (block phase, aliases both).
    float* c1 = ws + fixed;                      // 32*HW fl
    float* p3 = ws + fixed;                      // 32*HW2 fl (c1 dead when written)
    long avail_bytes = (long)ws_size - (long)fixed * 4;
    long per_block_bytes = (65536 + 65536 + 49152) * 2;  // 360448
    long cmax = avail_bytes / per_block_bytes;
    int chunk = (int)(cmax < 1 ? 1 : (cmax > NB ? NB : cmax));
    __hip_bfloat16* t1 = (__hip_bfloat16*)(ws + fixed);
    __hip_bfloat16* t2 = t1 + (long)chunk * 65536;
    __hip_bfloat16* t3 = t2 + (long)chunk * 65536;

    (void)hipFuncSetAttribute((const void*)k_first,
                              hipFuncAttributeMaxDynamicSharedMemorySize, 88856);
    (void)hipFuncSetAttribute((const void*)k_b2,
                              hipFuncAttributeMaxDynamicSharedMemorySize, 131072);
    (void)hipFuncSetAttribute((const void*)k_b3,
                              hipFuncAttributeMaxDynamicSharedMemorySize, 131072);

    k_pack<<<(WPK_TOT + 255) / 256, 256, 0, stream>>>(cx_w2, cx_w3, lt_w2, cx_w1, lt_w1, wpk);
    k_cls1<<<(HW + 255) / 256, 256, 0, stream>>>(x, cls_w1, cls_b1, c1);
    k_cls2c<<<dim3(600, 4), 256, 0, stream>>>(c1, cls_w2, cls_b2, c2);
    k_cls3<<<dim3(150, 2, 2), 256, 0, stream>>>(c2, cls_w3, cls_b3, p3);
    k_cls4f<<<150, 256, 0, stream>>>(p3, cls_w4, cls_b4, c4);
    k_cls5<<<1, 384, 0, stream>>>(c4, cls_w5, cls_b5, clsv, out + IMG_PIX);

    for (int b0 = 0; b0 < NB; b0 += chunk) {
        int n = chunk < (NB - b0) ? chunk : (NB - b0);
        k_first<<<n, 512, 88856, stream>>>(x, wpk, lt_b1, cx_b1, clsv, b0, t1);
        k_b2<<<n, 512, 131072, stream>>>(t1, wpk, cx_b2, lt_b2, clsv, b0, t2, t3);
        k_b3<<<n, 512, 131072, stream>>>(t2, wpk, cx_b3, clsv, b0, t3);
        k_assemble<<<(n * 19200 + 255) / 256, 256, 0, stream>>>(
            (const unsigned short*)t3, b0, n, out);
    }
}

// Round 9
// 254.378 us; speedup vs baseline: 1.3878x; 1.1020x over previous
//
#include <hip/hip_runtime.h>
#include <hip/hip_bf16.h>
#include <math.h>

static constexpr int H = 480, W = 320, NH = 24, NW = 16, NB = 384;
static constexpr int HW = H * W;            // 153600
static constexpr int H2 = 240, W2 = 160;
static constexpr int HW2 = H2 * W2;         // 38400
static constexpr int H4 = 120, W4 = 80;
static constexpr int HW4 = H4 * W4;         // 9600
static constexpr int IMG_PIX = 3 * 1920 * 1280;  // 7372800

typedef __attribute__((ext_vector_type(8))) short short8;
typedef __attribute__((ext_vector_type(4))) float f32x4;
typedef __attribute__((ext_vector_type(8))) unsigned short ushort8;

// packed-weight region offsets (ushort elements)
static constexpr int WPK_CX2 = 0;          // [64][9][64]
static constexpr int WPK_CX3 = 36864;      // [48][9][64]
static constexpr int WPK_LT2 = 64512;      // [48][9][32] (ci>=16 zero)
static constexpr int WPK_F_CX = 78336;     // [64][32] (k>=27 zero)
static constexpr int WPK_F_LT = 80384;     // [16][32]
static constexpr int WPK_TOT = 80896;
// cls2 split weights: 3 planes (h,m,l) x [32co][9tap][32ci]
static constexpr int WPK2 = 80896;
static constexpr int WPK2_PL = 9216;
static constexpr int WPK_ALL = WPK2 + 3 * WPK2_PL;  // 108544

__device__ __forceinline__ int iclamp(int v, int lo, int hi) {
    return v < lo ? lo : (v > hi ? hi : v);
}
__device__ __forceinline__ unsigned short f2bfu(float x) {
    __hip_bfloat16 h = __float2bfloat16(x);
    return *reinterpret_cast<unsigned short*>(&h);
}
__device__ __forceinline__ float bf2f(unsigned short u) {
    __hip_bfloat16 h = *reinterpret_cast<__hip_bfloat16*>(&u);
    return __bfloat162float(h);
}

// ---------------- weight pre-pack ----------------

__global__ __launch_bounds__(256) void k_pack(const float* __restrict__ cx_w2,
                                              const float* __restrict__ cx_w3,
                                              const float* __restrict__ lt_w2,
                                              const float* __restrict__ cx_w1,
                                              const float* __restrict__ lt_w1,
                                              const float* __restrict__ cls_w2,
                                              unsigned short* __restrict__ wpk) {
    int i = blockIdx.x * 256 + threadIdx.x;
    if (i >= WPK_ALL) return;
    if (i >= WPK2) {
        int j = i - WPK2;
        int plane = j / WPK2_PL, r = j % WPK2_PL;
        int co = r / 288, q = r % 288;
        int t = q / 32, ci = q % 32;
        float w = cls_w2[(co * 32 + ci) * 9 + t];
        unsigned short h = f2bfu(w);
        float r1 = w - bf2f(h);
        unsigned short m = f2bfu(r1);
        unsigned short l = f2bfu(r1 - bf2f(m));
        wpk[i] = plane == 0 ? h : (plane == 1 ? m : l);
        return;
    }
    float v = 0.f;
    if (i < WPK_CX3) {
        int co = i / 576, t = (i / 64) % 9, ci = i % 64;
        v = cx_w2[(co * 64 + ci) * 9 + t];
    } else if (i < WPK_LT2) {
        int j = i - WPK_CX3;
        int co = j / 576, t = (j / 64) % 9, ci = j % 64;
        v = cx_w3[(co * 64 + ci) * 9 + t];
    } else if (i < WPK_F_CX) {
        int j = i - WPK_LT2;
        int co = j / 288, t = (j / 32) % 9, ci = j % 32;
        v = (ci < 16) ? lt_w2[(co * 16 + ci) * 9 + t] : 0.f;
    } else if (i < WPK_F_LT) {
        int j = i - WPK_F_CX;
        int co = j >> 5, k = j & 31;
        v = (k < 27) ? cx_w1[co * 27 + k] : 0.f;
    } else {
        int j = i - WPK_F_LT;
        int co = j >> 5, k = j & 31;
        v = (k < 27) ? lt_w1[co * 27 + k] : 0.f;
    }
    wpk[i] = f2bfu(v);
}

// ---------------- classifier ----------------

// conv1 3->32 edge pad + relu; co-split x4; output as 3 split-bf16 planes,
// pixel-major [p*32+ci] (lossless h+m+l decomposition of the fp32 value).
__global__ __launch_bounds__(256) void k_cls1s(const float* __restrict__ x,
                                               const float* __restrict__ w,
                                               const float* __restrict__ b,
                                               unsigned short* __restrict__ c1s) {
    int p = blockIdx.x * 256 + threadIdx.x;
    if (p >= HW) return;
    int coc = blockIdx.y;  // 0..3
    int y = p / W, xx = p - y * W;
    float in[27];
#pragma unroll
    for (int ci = 0; ci < 3; ++ci)
#pragma unroll
        for (int dy = 0; dy < 3; ++dy) {
            int yy = iclamp(y + dy - 1, 0, H - 1);
#pragma unroll
            for (int dx = 0; dx < 3; ++dx) {
                int xc = iclamp(xx + dx - 1, 0, W - 1);
                in[ci * 9 + dy * 3 + dx] = x[ci * HW + yy * W + xc];
            }
        }
    ushort8 hv, mv, lv;
#pragma unroll
    for (int c8 = 0; c8 < 8; ++c8) {
        int co = coc * 8 + c8;
        float acc = b[co];
#pragma unroll
        for (int k = 0; k < 27; ++k) acc = fmaf(w[co * 27 + k], in[k], acc);
        float v = fmaxf(acc, 0.f);
        unsigned short h = f2bfu(v);
        float r1 = v - bf2f(h);
        unsigned short m = f2bfu(r1);
        unsigned short l = f2bfu(r1 - bf2f(m));
        hv[c8] = h; mv[c8] = m; lv[c8] = l;
    }
    *(ushort8*)(c1s + (long)p * 32 + coc * 8) = hv;
    *(ushort8*)(c1s + (long)32 * HW + (long)p * 32 + coc * 8) = mv;
    *(ushort8*)(c1s + (long)64 * HW + (long)p * 32 + coc * 8) = lv;
}

// one split-plane phase of the cls2 MFMA conv: stage halo for A-plane, run
// 9 taps x P weight-planes. P compile-time (rule #20).
template <int P>
__device__ __forceinline__ void cls2_phase(const unsigned short* __restrict__ src,
                                           unsigned short* __restrict__ sh2,
                                           const unsigned short* __restrict__ wb,
                                           f32x4 acc[4][2], int tid, int ty, int tx) {
    int lane = tid & 63, wave = tid >> 6;
    int col = lane & 15, kq = lane >> 4;
    __syncthreads();  // prior-phase reads complete before overwrite
    for (int idx = tid; idx < 1296; idx += 256) {
        int pix = idx >> 2, g = idx & 3;
        int hy = iclamp(ty * 16 + pix / 18 - 1, 0, H - 1);
        int hx = iclamp(tx * 16 + pix % 18 - 1, 0, W - 1);
        ushort8 v = *(const ushort8*)(src + ((long)(hy * W + hx)) * 32 + g * 8);
        *(ushort8*)(sh2 + pix * 32 + ((g ^ ((pix >> 1) & 3)) * 8)) = v;
    }
    __syncthreads();
#pragma unroll 1
    for (int t = 0; t < 9; ++t) {
        int dy = t / 3, dx = t - dy * 3;
        short8 B[2][P];
#pragma unroll
        for (int nt = 0; nt < 2; ++nt)
#pragma unroll
            for (int pl = 0; pl < P; ++pl)
                B[nt][pl] = *(const short8*)(wb + pl * WPK2_PL +
                                             ((nt * 16 + col) * 9 + t) * 32 + kq * 8);
#pragma unroll
        for (int i = 0; i < 4; ++i) {
            int pix = (wave * 4 + i + dy) * 18 + col + dx;
            short8 a = *(const short8*)(sh2 + pix * 32 + ((kq ^ ((pix >> 1) & 3)) * 8));
#pragma unroll
            for (int nt = 0; nt < 2; ++nt)
#pragma unroll
                for (int pl = 0; pl < P; ++pl)
                    acc[i][nt] = __builtin_amdgcn_mfma_f32_16x16x32_bf16(a, B[nt][pl],
                                                                         acc[i][nt], 0, 0, 0);
        }
    }
}

// conv2 32->32 edge pad + relu + 2x2 maxpool via split-bf16 MFMA (fp32-accurate).
// wg = 16x16 pre-pool tile (600 wgs, 4 waves). dyn LDS 32896 B.
__global__ __launch_bounds__(256, 2) void k_cls2m(const unsigned short* __restrict__ c1s,
                                                  const unsigned short* __restrict__ wpk,
                                                  const float* __restrict__ b2,
                                                  float* __restrict__ c2) {
    extern __shared__ unsigned short sh2[];
    int tid = threadIdx.x;
    int tile = blockIdx.x;  // 30 x 20
    int ty = tile / 20, tx = tile - ty * 20;
    int lane = tid & 63, wave = tid >> 6;
    int col = lane & 15, kq = lane >> 4;
    const unsigned short* wb = wpk + WPK2;
    f32x4 acc[4][2];
#pragma unroll
    for (int nt = 0; nt < 2; ++nt) {
        float bv = b2[nt * 16 + col];
#pragma unroll
        for (int i = 0; i < 4; ++i) acc[i][nt] = f32x4{bv, bv, bv, bv};
    }
    // A=h with W h,m,l; A=m with W h,m; A=l with W h.
    cls2_phase<3>(c1s, sh2, wb, acc, tid, ty, tx);
    cls2_phase<2>(c1s + (long)32 * HW, sh2, wb, acc, tid, ty, tx);
    cls2_phase<1>(c1s + (long)64 * HW, sh2, wb, acc, tid, ty, tx);
    __syncthreads();
    float* pool = (float*)sh2;  // [32co][257] floats = 32896 B (conflict-free stride)
#pragma unroll
    for (int i = 0; i < 4; ++i)
#pragma unroll
        for (int nt = 0; nt < 2; ++nt)
#pragma unroll
            for (int rr = 0; rr < 4; ++rr)
                pool[(nt * 16 + col) * 257 + (wave * 4 + i) * 16 + kq * 4 + rr] =
                    fmaxf(acc[i][nt][rr], 0.f);
    __syncthreads();
#pragma unroll
    for (int k = 0; k < 8; ++k) {
        int o = tid + k * 256;
        int co = o >> 6, rem = o & 63;
        int py = rem >> 3, px = rem & 7;
        const float* lp = pool + co * 257 + py * 32 + px * 2;
        float m = fmaxf(fmaxf(lp[0], lp[1]), fmaxf(lp[16], lp[17]));
        c2[co * HW2 + (ty * 8 + py) * W2 + tx * 8 + px] = m;
    }
}

// conv3 32->16 edge pad at 240x160; co-split x2 x ci-split x2 (fp32 partials).
__global__ __launch_bounds__(256) void k_cls3(const float* __restrict__ in,
                                              const float* __restrict__ w,
                                              const float* __restrict__ b,
                                              float* __restrict__ p3) {
    int p = blockIdx.x * 256 + threadIdx.x;
    if (p >= HW2) return;
    int cc = blockIdx.y;  // co chunk 0..1
    int s = blockIdx.z;   // ci half 0..1
    int y = p / W2, xx = p - y * W2;
    float acc[8];
#pragma unroll
    for (int co = 0; co < 8; ++co) acc[co] = s ? 0.f : b[cc * 8 + co];
    for (int cil = 0; cil < 16; ++cil) {
        int ci = s * 16 + cil;
        float v[9];
#pragma unroll
        for (int dy = 0; dy < 3; ++dy) {
            int yy = iclamp(y + dy - 1, 0, H2 - 1);
#pragma unroll
            for (int dx = 0; dx < 3; ++dx) {
                int xc = iclamp(xx + dx - 1, 0, W2 - 1);
                v[dy * 3 + dx] = in[ci * HW2 + yy * W2 + xc];
            }
        }
#pragma unroll
        for (int co = 0; co < 8; ++co)
#pragma unroll
            for (int k = 0; k < 9; ++k)
                acc[co] = fmaf(w[(cc * 8 + co) * 288 + ci * 9 + k], v[k], acc[co]);
    }
#pragma unroll
    for (int co = 0; co < 8; ++co) p3[(s * 16 + cc * 8 + co) * HW2 + p] = acc[co];
}

// fused (partial-sum + relu) -> conv4(16->8, edge pad) + relu + 2x2 maxpool.
__global__ __launch_bounds__(256) void k_cls4f(const float* __restrict__ p3,
                                               const float* __restrict__ w,
                                               const float* __restrict__ b,
                                               float* __restrict__ out) {
    __shared__ float lds[8 * 256];
    int t = threadIdx.x;
    int tile = blockIdx.x;           // 15 x 10 tiles
    int ty = tile / 10, tx = tile - ty * 10;
    int ly = t >> 4, lx = t & 15;
    int y = ty * 16 + ly, xx = tx * 16 + lx;
    float acc[8];
#pragma unroll
    for (int co = 0; co < 8; ++co) acc[co] = b[co];
    for (int ci = 0; ci < 16; ++ci) {
        float v[9];
#pragma unroll
        for (int dy = 0; dy < 3; ++dy) {
            int yy = iclamp(y + dy - 1, 0, H2 - 1);
#pragma unroll
            for (int dx = 0; dx < 3; ++dx) {
                int xc = iclamp(xx + dx - 1, 0, W2 - 1);
                int idx = ci * HW2 + yy * W2 + xc;
                v[dy * 3 + dx] = fmaxf(p3[idx] + p3[idx + 16 * HW2], 0.f);
            }
        }
#pragma unroll
        for (int co = 0; co < 8; ++co) {
            const float* wp = w + co * 144 + ci * 9;
#pragma unroll
            for (int k = 0; k < 9; ++k) acc[co] = fmaf(wp[k], v[k], acc[co]);
        }
    }
#pragma unroll
    for (int co = 0; co < 8; ++co) lds[co * 256 + t] = fmaxf(acc[co], 0.f);
    __syncthreads();
#pragma unroll
    for (int k = 0; k < 2; ++k) {
        int o = t + k * 256;
        int co = o >> 6, rem = o & 63;
        int py = rem >> 3, px = rem & 7;
        const float* lp = lds + co * 256 + py * 32 + px * 2;
        float m = fmaxf(fmaxf(lp[0], lp[1]), fmaxf(lp[16], lp[17]));
        out[co * HW4 + (ty * 8 + py) * W4 + tx * 8 + px] = m;
    }
}

__global__ __launch_bounds__(384) void k_cls5(const float* __restrict__ in,
                                              const float* __restrict__ w,
                                              const float* __restrict__ b,
                                              float* __restrict__ clsv,
                                              float* __restrict__ out_cls) {
    int tid = threadIdx.x;
    if (tid >= NB) return;
    int oy = tid / NW, ox = tid - oy * NW;
    float s = b[0];
    for (int ci = 0; ci < 8; ++ci)
#pragma unroll
        for (int ky = 0; ky < 5; ++ky)
#pragma unroll
            for (int kx = 0; kx < 5; ++kx)
                s = fmaf(w[ci * 25 + ky * 5 + kx],
                         in[ci * HW4 + (oy * 5 + ky) * W4 + (ox * 5 + kx)], s);
    float sig = 1.f / (1.f + expf(-s));
    clsv[tid] = sig;
    out_cls[tid] = sig;
}

// ---------------- block branches: bf16 MFMA ----------------

__global__ __launch_bounds__(512, 2) void k_first(const float* __restrict__ x,
                                                  const unsigned short* __restrict__ wpk,
                                                  const float* __restrict__ bl,
                                                  const float* __restrict__ bc,
                                                  const float* __restrict__ clsv,
                                                  int b0, __hip_bfloat16* __restrict__ t1) {
    extern __shared__ unsigned short sh[];
    unsigned short* A = sh;                 // 1024*40
    unsigned short* halo = sh + 1024 * 40;  // 3*1156
    int bL = blockIdx.x, b = b0 + bL;
    bool cx = clsv[b] > 0.5f;
    int bh = b / NW, bw = b - bh * NW;
    int tid = threadIdx.x;
    for (int i = tid; i < 3 * 1156; i += 512) {
        int ci = i / 1156, rem = i - ci * 1156;
        int ry = rem / 34, rx = rem - ry * 34;
        int yg = bh * 20 + ry - 7, xg = bw * 20 + rx - 7;
        float v = ((unsigned)yg < (unsigned)H && (unsigned)xg < (unsigned)W)
                      ? x[ci * HW + yg * W + xg] : 0.f;
        halo[i] = f2bfu(v);
    }
    __syncthreads();
    for (int v = tid; v < 1024 * 32; v += 512) {
        int p = v >> 5, k = v & 31;
        unsigned short val = 0;
        if (k < 27) {
            int ci = k / 9, t = k - ci * 9;
            int dy = t / 3, dx = t - dy * 3;
            int y = p >> 5, xx = p & 31;
            val = halo[ci * 1156 + (y + dy) * 34 + (xx + dx)];
        }
        A[p * 40 + k] = val;
    }
    __syncthreads();
    int lane = tid & 63, wave = tid >> 6;
    int col = lane & 15, kq = lane >> 4;
    const unsigned short* wf = wpk + (cx ? WPK_F_CX : WPK_F_LT);
    const float* bi = cx ? bc : bl;
    int nT = cx ? 4 : 1;
    __hip_bfloat16* outb = t1 + (long)bL * 65536;
    for (int nt = 0; nt < nT; ++nt) {
        int co = nt * 16 + col;
        short8 Bf = *(const short8*)(wf + co * 32 + kq * 8);
        float bv = bi[co];
#pragma unroll 1
        for (int i = 0; i < 8; ++i) {
            int mt = wave * 8 + i;
            short8 a = *(const short8*)(A + (mt * 16 + col) * 40 + kq * 8);
            f32x4 acc = {bv, bv, bv, bv};
            acc = __builtin_amdgcn_mfma_f32_16x16x32_bf16(a, Bf, acc, 0, 0, 0);
            int prow = mt * 16 + kq * 4;
#pragma unroll
            for (int r = 0; r < 4; ++r)
                outb[(prow + r) * 64 + co] = __float2bfloat16(fmaxf(acc[r], 0.f));
        }
    }
}

// taps-outer conv over one 32x32 block from XOR-swizzled LDS.
template <int CINP, int NT, int GOUT, bool RELU>
__device__ __forceinline__ void conv_mfma(const unsigned short* __restrict__ sh,
                                          const unsigned short* __restrict__ wpk,
                                          const float* __restrict__ bias,
                                          unsigned short* __restrict__ outg, int tid) {
    constexpr int KC = CINP / 32;
    int lane = tid & 63, wave = tid >> 6;
    int col = lane & 15, kq = lane >> 4;
    f32x4 acc[8][NT];
#pragma unroll
    for (int nt = 0; nt < NT; ++nt) {
        float bv = bias[nt * 16 + col];
#pragma unroll
        for (int i = 0; i < 8; ++i) acc[i][nt] = f32x4{bv, bv, bv, bv};
    }
#pragma unroll 1
    for (int t = 0; t < 9; ++t) {
        int dy = t / 3, dx = t - dy * 3;
        short8 B[NT][KC];
#pragma unroll
        for (int nt = 0; nt < NT; ++nt)
#pragma unroll
            for (int kc = 0; kc < KC; ++kc)
                B[nt][kc] = *(const short8*)(wpk + ((nt * 16 + col) * 9 + t) * CINP +
                                             kc * 32 + kq * 8);
#pragma unroll
        for (int i = 0; i < 8; ++i) {
            int mt = wave * 8 + i;
            int yp = (mt >> 1) + dy - 1;
            if ((unsigned)yp > 31u) continue;  // wave-uniform skip
            int xs = ((mt & 1) << 4) + col + dx - 1;
            bool xv = (unsigned)xs < 32u;
            int xc = xs < 0 ? 0 : (xs > 31 ? 31 : xs);
            int pr = yp * 32 + xc;
#pragma unroll
            for (int kc = 0; kc < KC; ++kc) {
                int c = kc * 4 + kq;
                int cs = (CINP == 64) ? (c ^ (pr & 7)) : (c ^ ((pr >> 1) & 3));
                short8 a = *(const short8*)(sh + pr * CINP + cs * 8);
                if (!xv) a = short8{0, 0, 0, 0, 0, 0, 0, 0};
#pragma unroll
                for (int nt = 0; nt < NT; ++nt)
                    acc[i][nt] = __builtin_amdgcn_mfma_f32_16x16x32_bf16(a, B[nt][kc],
                                                                         acc[i][nt], 0, 0, 0);
            }
        }
    }
#pragma unroll
    for (int i = 0; i < 8; ++i) {
        int prow = (wave * 8 + i) * 16 + kq * 4;
#pragma unroll
        for (int nt = 0; nt < NT; ++nt) {
            int co = nt * 16 + col;
#pragma unroll
            for (int r = 0; r < 4; ++r) {
                float v = acc[i][nt][r];
                if (RELU) v = fmaxf(v, 0.f);
                outg[(prow + r) * GOUT + co] = f2bfu(v);
            }
        }
    }
}

// merged second conv: cx blocks do 64->64 (t1->t2, relu); lt blocks do 16->48 (t1->t3).
__global__ __launch_bounds__(512, 2) void k_b2(const __hip_bfloat16* __restrict__ t1,
                                               const unsigned short* __restrict__ wpk,
                                               const float* __restrict__ cx_b2,
                                               const float* __restrict__ lt_b2,
                                               const float* __restrict__ clsv, int b0,
                                               __hip_bfloat16* __restrict__ t2,
                                               __hip_bfloat16* __restrict__ t3) {
    extern __shared__ unsigned short sh[];
    int bL = blockIdx.x;
    bool cx = clsv[b0 + bL] > 0.5f;
    int tid = threadIdx.x;
    const unsigned short* inb = (const unsigned short*)t1 + (long)bL * 65536;
    if (cx) {
        for (int u = tid; u < 8192; u += 512) {
            int p = u >> 3, c = u & 7;
            *(ushort8*)(sh + p * 64 + (c ^ (p & 7)) * 8) =
                *(const ushort8*)(inb + p * 64 + c * 8);
        }
        __syncthreads();
        conv_mfma<64, 4, 64, true>(sh, wpk + WPK_CX2, cx_b2,
                                   (unsigned short*)t2 + (long)bL * 65536, tid);
    } else {
        ushort8 z = {0, 0, 0, 0, 0, 0, 0, 0};
        for (int u = tid; u < 4096; u += 512) {
            int p = u >> 2, c = u & 3;
            ushort8 v = (c < 2) ? *(const ushort8*)(inb + p * 64 + c * 8) : z;
            *(ushort8*)(sh + p * 32 + (c ^ ((p >> 1) & 3)) * 8) = v;
        }
        __syncthreads();
        conv_mfma<32, 3, 48, false>(sh, wpk + WPK_LT2, lt_b2,
                                    (unsigned short*)t3 + (long)bL * 49152, tid);
    }
}

// third conv, cx only: 64->48 (t2->t3).
__global__ __launch_bounds__(512, 2) void k_b3(const __hip_bfloat16* __restrict__ t2,
                                               const unsigned short* __restrict__ wpk,
                                               const float* __restrict__ cx_b3,
                                               const float* __restrict__ clsv, int b0,
                                               __hip_bfloat16* __restrict__ t3) {
    extern __shared__ unsigned short sh[];
    int bL = blockIdx.x;
    if (!(clsv[b0 + bL] > 0.5f)) return;
    int tid = threadIdx.x;
    const unsigned short* inb = (const unsigned short*)t2 + (long)bL * 65536;
    for (int u = tid; u < 8192; u += 512) {
        int p = u >> 3, c = u & 7;
        *(ushort8*)(sh + p * 64 + (c ^ (p & 7)) * 8) = *(const ushort8*)(inb + p * 64 + c * 8);
    }
    __syncthreads();
    conv_mfma<64, 3, 48, false>(sh, wpk + WPK_CX3, cx_b3,
                                (unsigned short*)t3 + (long)bL * 49152, tid);
}

// pixel shuffle + clip + crop + reassemble from bf16 t3 [p][48]
__global__ __launch_bounds__(256) void k_assemble(const unsigned short* __restrict__ t3,
                                                  int b0, int nb, float* __restrict__ out) {
    int idx = blockIdx.x * 256 + threadIdx.x;
    if (idx >= nb * 19200) return;
    int bL = idx / 19200;
    int rem = idx - bL * 19200;
    int ch = rem / 6400;
    int rem2 = rem - ch * 6400;
    int r = rem2 / 80, s = rem2 - r * 80;
    int b = b0 + bL;
    int bh = b / NW, bw = b - bh * NW;
    int yy = r + 24, xx = s + 24;
    int pc = ch * 16 + (yy & 3) * 4 + (xx & 3);
    float v = bf2f(t3[(long)bL * 49152 + ((yy >> 2) * 32 + (xx >> 2)) * 48 + pc]);
    v = fminf(fmaxf(v, 0.f), 1.f);
    out[ch * (1920 * 1280) + (bh * 80 + r) * 1280 + (bw * 80 + s)] = v;
}

extern "C" void kernel_launch(void* const* d_in, const int* in_sizes, int n_in,
                              void* d_out, int out_size, void* d_ws, size_t ws_size,
                              hipStream_t stream) {
    const float* x      = (const float*)d_in[0];
    const float* cls_w1 = (const float*)d_in[1];
    const float* cls_b1 = (const float*)d_in[2];
    const float* cls_w2 = (const float*)d_in[3];
    const float* cls_b2 = (const float*)d_in[4];
    const float* cls_w3 = (const float*)d_in[5];
    const float* cls_b3 = (const float*)d_in[6];
    const float* cls_w4 = (const float*)d_in[7];
    const float* cls_b4 = (const float*)d_in[8];
    const float* cls_w5 = (const float*)d_in[9];
    const float* cls_b5 = (const float*)d_in[10];
    const float* lt_w1  = (const float*)d_in[11];
    const float* lt_b1  = (const float*)d_in[12];
    const float* lt_w2  = (const float*)d_in[13];
    const float* lt_b2  = (const float*)d_in[14];
    const float* cx_w1  = (const float*)d_in[15];
    const float* cx_b1  = (const float*)d_in[16];
    const float* cx_w2  = (const float*)d_in[17];
    const float* cx_b2  = (const float*)d_in[18];
    const float* cx_w3  = (const float*)d_in[19];
    const float* cx_b3  = (const float*)d_in[20];

    float* ws = (float*)d_ws;
    float* out = (float*)d_out;

    // persistent small buffers
    size_t off = 0;
    float* c2 = ws + off;   off += (size_t)32 * HW2;   // 1,228,800
    float* c4 = ws + off;   off += (size_t)8 * HW4;    //    76,800
    float* clsv = ws + off; off += 384;
    unsigned short* wpk = (unsigned short*)(ws + off); off += (WPK_ALL + 1) / 2;
    size_t fixed = off;

    // scratch: c1 split planes (classifier), p3 after them; block phase aliases all.
    unsigned short* c1s = (unsigned short*)(ws + fixed);   // 96*HW shorts = 48*HW floats
    float* p3 = ws + fixed + (size_t)48 * HW;              // 32*HW2 floats
    long avail_bytes = (long)ws_size - (long)fixed * 4;
    long per_block_bytes = (65536 + 65536 + 49152) * 2;  // 360448
    long cmax = avail_bytes / per_block_bytes;
    int chunk = (int)(cmax < 1 ? 1 : (cmax > NB ? NB : cmax));
    __hip_bfloat16* t1 = (__hip_bfloat16*)(ws + fixed);
    __hip_bfloat16* t2 = t1 + (long)chunk * 65536;
    __hip_bfloat16* t3 = t2 + (long)chunk * 65536;

    (void)hipFuncSetAttribute((const void*)k_first,
                              hipFuncAttributeMaxDynamicSharedMemorySize, 88856);
    (void)hipFuncSetAttribute((const void*)k_b2,
                              hipFuncAttributeMaxDynamicSharedMemorySize, 131072);
    (void)hipFuncSetAttribute((const void*)k_b3,
                              hipFuncAttributeMaxDynamicSharedMemorySize, 131072);
    (void)hipFuncSetAttribute((const void*)k_cls2m,
                              hipFuncAttributeMaxDynamicSharedMemorySize, 32896);

    k_pack<<<(WPK_ALL + 255) / 256, 256, 0, stream>>>(cx_w2, cx_w3, lt_w2, cx_w1, lt_w1,
                                                      cls_w2, wpk);
    k_cls1s<<<dim3((HW + 255) / 256, 4), 256, 0, stream>>>(x, cls_w1, cls_b1, c1s);
    k_cls2m<<<600, 256, 32896, stream>>>(c1s, wpk, cls_b2, c2);
    k_cls3<<<dim3(150, 2, 2), 256, 0, stream>>>(c2, cls_w3, cls_b3, p3);
    k_cls4f<<<150, 256, 0, stream>>>(p3, cls_w4, cls_b4, c4);
    k_cls5<<<1, 384, 0, stream>>>(c4, cls_w5, cls_b5, clsv, out + IMG_PIX);

    for (int b0 = 0; b0 < NB; b0 += chunk) {
        int n = chunk < (NB - b0) ? chunk : (NB - b0);
        k_first<<<n, 512, 88856, stream>>>(x, wpk, lt_b1, cx_b1, clsv, b0, t1);
        k_b2<<<n, 512, 131072, stream>>>(t1, wpk, cx_b2, lt_b2, clsv, b0, t2, t3);
        k_b3<<<n, 512, 131072, stream>>>(t2, wpk, cx_b3, clsv, b0, t3);
        k_assemble<<<(n * 19200 + 255) / 256, 256, 0, stream>>>(
            (const unsigned short*)t3, b0, n, out);
    }
}

// Round 10
// 230.335 us; speedup vs baseline: 1.5327x; 1.1044x over previous
//
#include <hip/hip_runtime.h>
#include <hip/hip_bf16.h>
#include <math.h>

static constexpr int H = 480, W = 320, NH = 24, NW = 16, NB = 384;
static constexpr int HW = H * W;            // 153600
static constexpr int H2 = 240, W2 = 160;
static constexpr int HW2 = H2 * W2;         // 38400
static constexpr int H4 = 120, W4 = 80;
static constexpr int HW4 = H4 * W4;         // 9600
static constexpr int IMG_PIX = 3 * 1920 * 1280;  // 7372800

typedef __attribute__((ext_vector_type(8))) short short8;
typedef __attribute__((ext_vector_type(4))) float f32x4;
typedef __attribute__((ext_vector_type(8))) unsigned short ushort8;

// packed-weight region offsets (ushort elements)
static constexpr int WPK_CX2 = 0;          // [64][9][64]
static constexpr int WPK_CX3 = 36864;      // [48][9][64]
static constexpr int WPK_LT2 = 64512;      // [48][9][32] (ci>=16 zero)
static constexpr int WPK_F_CX = 78336;     // [64][32] (k>=27 zero)
static constexpr int WPK_F_LT = 80384;     // [16][32]
static constexpr int WPK_TOT = 80896;
// cls2 split weights: 3 planes (h,m,l) x [32co][9tap][32ci]
static constexpr int WPK2 = 80896;
static constexpr int WPK2_PL = 9216;
static constexpr int WPK_ALL = WPK2 + 3 * WPK2_PL;  // 108544

__device__ __forceinline__ int iclamp(int v, int lo, int hi) {
    return v < lo ? lo : (v > hi ? hi : v);
}
__device__ __forceinline__ unsigned short f2bfu(float x) {
    __hip_bfloat16 h = __float2bfloat16(x);
    return *reinterpret_cast<unsigned short*>(&h);
}
__device__ __forceinline__ float bf2f(unsigned short u) {
    __hip_bfloat16 h = *reinterpret_cast<__hip_bfloat16*>(&u);
    return __bfloat162float(h);
}

// ---------------- weight pre-pack ----------------

__global__ __launch_bounds__(256) void k_pack(const float* __restrict__ cx_w2,
                                              const float* __restrict__ cx_w3,
                                              const float* __restrict__ lt_w2,
                                              const float* __restrict__ cx_w1,
                                              const float* __restrict__ lt_w1,
                                              const float* __restrict__ cls_w2,
                                              unsigned short* __restrict__ wpk) {
    int i = blockIdx.x * 256 + threadIdx.x;
    if (i >= WPK_ALL) return;
    if (i >= WPK2) {
        int j = i - WPK2;
        int plane = j / WPK2_PL, r = j % WPK2_PL;
        int co = r / 288, q = r % 288;
        int t = q / 32, ci = q % 32;
        float w = cls_w2[(co * 32 + ci) * 9 + t];
        unsigned short h = f2bfu(w);
        float r1 = w - bf2f(h);
        unsigned short m = f2bfu(r1);
        unsigned short l = f2bfu(r1 - bf2f(m));
        wpk[i] = plane == 0 ? h : (plane == 1 ? m : l);
        return;
    }
    float v = 0.f;
    if (i < WPK_CX3) {
        int co = i / 576, t = (i / 64) % 9, ci = i % 64;
        v = cx_w2[(co * 64 + ci) * 9 + t];
    } else if (i < WPK_LT2) {
        int j = i - WPK_CX3;
        int co = j / 576, t = (j / 64) % 9, ci = j % 64;
        v = cx_w3[(co * 64 + ci) * 9 + t];
    } else if (i < WPK_F_CX) {
        int j = i - WPK_LT2;
        int co = j / 288, t = (j / 32) % 9, ci = j % 32;
        v = (ci < 16) ? lt_w2[(co * 16 + ci) * 9 + t] : 0.f;
    } else if (i < WPK_F_LT) {
        int j = i - WPK_F_CX;
        int co = j >> 5, k = j & 31;
        v = (k < 27) ? cx_w1[co * 27 + k] : 0.f;
    } else {
        int j = i - WPK_F_LT;
        int co = j >> 5, k = j & 31;
        v = (k < 27) ? lt_w1[co * 27 + k] : 0.f;
    }
    wpk[i] = f2bfu(v);
}

// ---------------- classifier ----------------

__global__ __launch_bounds__(256) void k_cls1s(const float* __restrict__ x,
                                               const float* __restrict__ w,
                                               const float* __restrict__ b,
                                               unsigned short* __restrict__ c1s) {
    int p = blockIdx.x * 256 + threadIdx.x;
    if (p >= HW) return;
    int coc = blockIdx.y;  // 0..3
    int y = p / W, xx = p - y * W;
    float in[27];
#pragma unroll
    for (int ci = 0; ci < 3; ++ci)
#pragma unroll
        for (int dy = 0; dy < 3; ++dy) {
            int yy = iclamp(y + dy - 1, 0, H - 1);
#pragma unroll
            for (int dx = 0; dx < 3; ++dx) {
                int xc = iclamp(xx + dx - 1, 0, W - 1);
                in[ci * 9 + dy * 3 + dx] = x[ci * HW + yy * W + xc];
            }
        }
    ushort8 hv, mv, lv;
#pragma unroll
    for (int c8 = 0; c8 < 8; ++c8) {
        int co = coc * 8 + c8;
        float acc = b[co];
#pragma unroll
        for (int k = 0; k < 27; ++k) acc = fmaf(w[co * 27 + k], in[k], acc);
        float v = fmaxf(acc, 0.f);
        unsigned short h = f2bfu(v);
        float r1 = v - bf2f(h);
        unsigned short m = f2bfu(r1);
        unsigned short l = f2bfu(r1 - bf2f(m));
        hv[c8] = h; mv[c8] = m; lv[c8] = l;
    }
    *(ushort8*)(c1s + (long)p * 32 + coc * 8) = hv;
    *(ushort8*)(c1s + (long)32 * HW + (long)p * 32 + coc * 8) = mv;
    *(ushort8*)(c1s + (long)64 * HW + (long)p * 32 + coc * 8) = lv;
}

template <int P>
__device__ __forceinline__ void cls2_phase(const unsigned short* __restrict__ src,
                                           unsigned short* __restrict__ sh2,
                                           const unsigned short* __restrict__ wb,
                                           f32x4 acc[4][2], int tid, int ty, int tx) {
    int lane = tid & 63, wave = tid >> 6;
    int col = lane & 15, kq = lane >> 4;
    __syncthreads();
    for (int idx = tid; idx < 1296; idx += 256) {
        int pix = idx >> 2, g = idx & 3;
        int hy = iclamp(ty * 16 + pix / 18 - 1, 0, H - 1);
        int hx = iclamp(tx * 16 + pix % 18 - 1, 0, W - 1);
        ushort8 v = *(const ushort8*)(src + ((long)(hy * W + hx)) * 32 + g * 8);
        *(ushort8*)(sh2 + pix * 32 + ((g ^ ((pix >> 1) & 3)) * 8)) = v;
    }
    __syncthreads();
#pragma unroll 1
    for (int t = 0; t < 9; ++t) {
        int dy = t / 3, dx = t - dy * 3;
        short8 B[2][P];
#pragma unroll
        for (int nt = 0; nt < 2; ++nt)
#pragma unroll
            for (int pl = 0; pl < P; ++pl)
                B[nt][pl] = *(const short8*)(wb + pl * WPK2_PL +
                                             ((nt * 16 + col) * 9 + t) * 32 + kq * 8);
#pragma unroll
        for (int i = 0; i < 4; ++i) {
            int pix = (wave * 4 + i + dy) * 18 + col + dx;
            short8 a = *(const short8*)(sh2 + pix * 32 + ((kq ^ ((pix >> 1) & 3)) * 8));
#pragma unroll
            for (int nt = 0; nt < 2; ++nt)
#pragma unroll
                for (int pl = 0; pl < P; ++pl)
                    acc[i][nt] = __builtin_amdgcn_mfma_f32_16x16x32_bf16(a, B[nt][pl],
                                                                         acc[i][nt], 0, 0, 0);
        }
    }
}

__global__ __launch_bounds__(256, 2) void k_cls2m(const unsigned short* __restrict__ c1s,
                                                  const unsigned short* __restrict__ wpk,
                                                  const float* __restrict__ b2,
                                                  float* __restrict__ c2) {
    extern __shared__ unsigned short sh2[];
    int tid = threadIdx.x;
    int tile = blockIdx.x;  // 30 x 20
    int ty = tile / 20, tx = tile - ty * 20;
    int lane = tid & 63, wave = tid >> 6;
    int col = lane & 15, kq = lane >> 4;
    const unsigned short* wb = wpk + WPK2;
    f32x4 acc[4][2];
#pragma unroll
    for (int nt = 0; nt < 2; ++nt) {
        float bv = b2[nt * 16 + col];
#pragma unroll
        for (int i = 0; i < 4; ++i) acc[i][nt] = f32x4{bv, bv, bv, bv};
    }
    cls2_phase<3>(c1s, sh2, wb, acc, tid, ty, tx);
    cls2_phase<2>(c1s + (long)32 * HW, sh2, wb, acc, tid, ty, tx);
    cls2_phase<1>(c1s + (long)64 * HW, sh2, wb, acc, tid, ty, tx);
    __syncthreads();
    float* pool = (float*)sh2;  // [32co][257]
#pragma unroll
    for (int i = 0; i < 4; ++i)
#pragma unroll
        for (int nt = 0; nt < 2; ++nt)
#pragma unroll
            for (int rr = 0; rr < 4; ++rr)
                pool[(nt * 16 + col) * 257 + (wave * 4 + i) * 16 + kq * 4 + rr] =
                    fmaxf(acc[i][nt][rr], 0.f);
    __syncthreads();
#pragma unroll
    for (int k = 0; k < 8; ++k) {
        int o = tid + k * 256;
        int co = o >> 6, rem = o & 63;
        int py = rem >> 3, px = rem & 7;
        const float* lp = pool + co * 257 + py * 32 + px * 2;
        float m = fmaxf(fmaxf(lp[0], lp[1]), fmaxf(lp[16], lp[17]));
        c2[co * HW2 + (ty * 8 + py) * W2 + tx * 8 + px] = m;
    }
}

__global__ __launch_bounds__(256) void k_cls3(const float* __restrict__ in,
                                              const float* __restrict__ w,
                                              const float* __restrict__ b,
                                              float* __restrict__ p3) {
    int p = blockIdx.x * 256 + threadIdx.x;
    if (p >= HW2) return;
    int cc = blockIdx.y;  // 0..1
    int s = blockIdx.z;   // 0..1
    int y = p / W2, xx = p - y * W2;
    float acc[8];
#pragma unroll
    for (int co = 0; co < 8; ++co) acc[co] = s ? 0.f : b[cc * 8 + co];
    for (int cil = 0; cil < 16; ++cil) {
        int ci = s * 16 + cil;
        float v[9];
#pragma unroll
        for (int dy = 0; dy < 3; ++dy) {
            int yy = iclamp(y + dy - 1, 0, H2 - 1);
#pragma unroll
            for (int dx = 0; dx < 3; ++dx) {
                int xc = iclamp(xx + dx - 1, 0, W2 - 1);
                v[dy * 3 + dx] = in[ci * HW2 + yy * W2 + xc];
            }
        }
#pragma unroll
        for (int co = 0; co < 8; ++co)
#pragma unroll
            for (int k = 0; k < 9; ++k)
                acc[co] = fmaf(w[(cc * 8 + co) * 288 + ci * 9 + k], v[k], acc[co]);
    }
#pragma unroll
    for (int co = 0; co < 8; ++co) p3[(s * 16 + cc * 8 + co) * HW2 + p] = acc[co];
}

__global__ __launch_bounds__(256) void k_cls4f(const float* __restrict__ p3,
                                               const float* __restrict__ w,
                                               const float* __restrict__ b,
                                               float* __restrict__ out) {
    __shared__ float lds[8 * 256];
    int t = threadIdx.x;
    int tile = blockIdx.x;           // 15 x 10 tiles
    int ty = tile / 10, tx = tile - ty * 10;
    int ly = t >> 4, lx = t & 15;
    int y = ty * 16 + ly, xx = tx * 16 + lx;
    float acc[8];
#pragma unroll
    for (int co = 0; co < 8; ++co) acc[co] = b[co];
    for (int ci = 0; ci < 16; ++ci) {
        float v[9];
#pragma unroll
        for (int dy = 0; dy < 3; ++dy) {
            int yy = iclamp(y + dy - 1, 0, H2 - 1);
#pragma unroll
            for (int dx = 0; dx < 3; ++dx) {
                int xc = iclamp(xx + dx - 1, 0, W2 - 1);
                int idx = ci * HW2 + yy * W2 + xc;
                v[dy * 3 + dx] = fmaxf(p3[idx] + p3[idx + 16 * HW2], 0.f);
            }
        }
#pragma unroll
        for (int co = 0; co < 8; ++co) {
            const float* wp = w + co * 144 + ci * 9;
#pragma unroll
            for (int k = 0; k < 9; ++k) acc[co] = fmaf(wp[k], v[k], acc[co]);
        }
    }
#pragma unroll
    for (int co = 0; co < 8; ++co) lds[co * 256 + t] = fmaxf(acc[co], 0.f);
    __syncthreads();
#pragma unroll
    for (int k = 0; k < 2; ++k) {
        int o = t + k * 256;
        int co = o >> 6, rem = o & 63;
        int py = rem >> 3, px = rem & 7;
        const float* lp = lds + co * 256 + py * 32 + px * 2;
        float m = fmaxf(fmaxf(lp[0], lp[1]), fmaxf(lp[16], lp[17]));
        out[co * HW4 + (ty * 8 + py) * W4 + tx * 8 + px] = m;
    }
}

__global__ __launch_bounds__(384) void k_cls5(const float* __restrict__ in,
                                              const float* __restrict__ w,
                                              const float* __restrict__ b,
                                              float* __restrict__ clsv,
                                              float* __restrict__ out_cls) {
    int tid = threadIdx.x;
    if (tid >= NB) return;
    int oy = tid / NW, ox = tid - oy * NW;
    float s = b[0];
    for (int ci = 0; ci < 8; ++ci)
#pragma unroll
        for (int ky = 0; ky < 5; ++ky)
#pragma unroll
            for (int kx = 0; kx < 5; ++kx)
                s = fmaf(w[ci * 25 + ky * 5 + kx],
                         in[ci * HW4 + (oy * 5 + ky) * W4 + (ox * 5 + kx)], s);
    float sig = 1.f / (1.f + expf(-s));
    clsv[tid] = sig;
    out_cls[tid] = sig;
}

// ---------------- fully fused block path ----------------
// One wg per half-block (grid = 768). conv1 -> T1(LDS) -> conv2 -> T2(LDS)
// -> conv3 -> pixel-shuffle/crop/clip -> out. lt: conv1 -> T1 -> conv2 -> out.
// LDS: T1 [20*32][64] (81920B) + T2 [18*32][64] (73728B) + XH [3][20][34]
// (4080B) = 159728 B.
__global__ __launch_bounds__(512, 2) void k_block(const float* __restrict__ x,
                                                  const unsigned short* __restrict__ wpk,
                                                  const float* __restrict__ lt_b1,
                                                  const float* __restrict__ cx_b1,
                                                  const float* __restrict__ lt_b2,
                                                  const float* __restrict__ cx_b2,
                                                  const float* __restrict__ cx_b3,
                                                  const float* __restrict__ clsv,
                                                  float* __restrict__ out) {
    extern __shared__ unsigned short sh[];
    unsigned short* T1 = sh;           // 40960 shorts
    unsigned short* T2 = sh + 40960;   // 36864 shorts
    unsigned short* XH = sh + 77824;   // 2040 shorts
    int wg = blockIdx.x;
    int b = wg >> 1, half = wg & 1;
    bool cx = clsv[b] > 0.5f;
    int bh = b / NW, bw = b - bh * NW;
    int base = half << 4;              // first output row of this half
    int vlo = half ? 14 : 0;           // first valid t1 block-row in tile
    int troff = half ? 0 : 2;          // valid t1 rows start at tile row troff
    int tid = threadIdx.x;
    int lane = tid & 63, wave = tid >> 6;
    int col = lane & 15, kq = lane >> 4;

    // ---- phase 0: zero T1(+T2), stage x halo ----
    {
        int zn = cx ? 9728 : 2560;  // ushort8 units from sh
        ushort8 z = {0, 0, 0, 0, 0, 0, 0, 0};
        for (int i = tid; i < zn; i += 512) *(ushort8*)(sh + i * 8) = z;
        for (int i = tid; i < 680; i += 512) {
            int xr = i / 34, xcc = i - xr * 34;
            int yg = bh * 20 + (vlo - 1 + xr) - 6;
            int xg = bw * 20 + (xcc - 1) - 6;
            bool ok = (unsigned)yg < (unsigned)H && (unsigned)xg < (unsigned)W;
#pragma unroll
            for (int ci = 0; ci < 3; ++ci)
                XH[ci * 680 + i] = ok ? f2bfu(x[ci * HW + yg * W + xg])
                                      : (unsigned short)0;
        }
    }
    __syncthreads();

    // ---- phase 1: conv1 via MFMA (18 valid rows = 36 m-tiles) ----
    if (cx) {
        short8 Bf[4];
        float bv[4];
#pragma unroll
        for (int nt = 0; nt < 4; ++nt) {
            Bf[nt] = *(const short8*)(wpk + WPK_F_CX + (nt * 16 + col) * 32 + kq * 8);
            bv[nt] = cx_b1[nt * 16 + col];
        }
#pragma unroll
        for (int i = 0; i < 5; ++i) {
            int mt = wave + 8 * i;
            if (mt >= 36) break;
            int rr = mt >> 1, xc0 = (mt & 1) << 4;
            short8 av;
#pragma unroll
            for (int j = 0; j < 8; ++j) {
                int k = kq * 8 + j;
                int kk = k < 27 ? k : 0;
                int ci = kk / 9, t = kk - ci * 9;
                int dy = t / 3, dx = t - dy * 3;
                unsigned short v = XH[ci * 680 + (rr + dy) * 34 + (xc0 + col + dx)];
                av[j] = (k < 27) ? (short)v : (short)0;
            }
#pragma unroll
            for (int nt = 0; nt < 4; ++nt) {
                f32x4 acc = {bv[nt], bv[nt], bv[nt], bv[nt]};
                acc = __builtin_amdgcn_mfma_f32_16x16x32_bf16(av, Bf[nt], acc, 0, 0, 0);
                int co = nt * 16 + col;
#pragma unroll
                for (int r = 0; r < 4; ++r) {
                    int p = mt * 16 + kq * 4 + r;
                    int p1 = (rr + troff) * 32 + (p & 31);
                    T1[p1 * 64 + (((co >> 3) ^ (p1 & 7)) << 3) + (co & 7)] =
                        f2bfu(fmaxf(acc[r], 0.f));
                }
            }
        }
    } else {
        short8 Bf = *(const short8*)(wpk + WPK_F_LT + col * 32 + kq * 8);
        float bv = lt_b1[col];
#pragma unroll
        for (int i = 0; i < 5; ++i) {
            int mt = wave + 8 * i;
            if (mt >= 36) break;
            int rr = mt >> 1, xc0 = (mt & 1) << 4;
            short8 av;
#pragma unroll
            for (int j = 0; j < 8; ++j) {
                int k = kq * 8 + j;
                int kk = k < 27 ? k : 0;
                int ci = kk / 9, t = kk - ci * 9;
                int dy = t / 3, dx = t - dy * 3;
                unsigned short v = XH[ci * 680 + (rr + dy) * 34 + (xc0 + col + dx)];
                av[j] = (k < 27) ? (short)v : (short)0;
            }
            f32x4 acc = {bv, bv, bv, bv};
            acc = __builtin_amdgcn_mfma_f32_16x16x32_bf16(av, Bf, acc, 0, 0, 0);
#pragma unroll
            for (int r = 0; r < 4; ++r) {
                int p = mt * 16 + kq * 4 + r;
                int p1 = (rr + troff) * 32 + (p & 31);
                T1[p1 * 32 + (((col >> 3) ^ ((p1 >> 1) & 3)) << 3) + (col & 7)] =
                    f2bfu(fmaxf(acc[r], 0.f));
            }
        }
    }
    __syncthreads();

    if (cx) {
        // ---- phase 2: conv2 64->64 (T1 -> T2), relu ----
        {
            f32x4 acc[5][4];
#pragma unroll
            for (int nt = 0; nt < 4; ++nt) {
                float bv = cx_b2[nt * 16 + col];
#pragma unroll
                for (int i = 0; i < 5; ++i) acc[i][nt] = f32x4{bv, bv, bv, bv};
            }
#pragma unroll 1
            for (int t = 0; t < 9; ++t) {
                int dy = t / 3, dx = t - dy * 3;
                short8 B[4][2];
#pragma unroll
                for (int nt = 0; nt < 4; ++nt)
#pragma unroll
                    for (int kc = 0; kc < 2; ++kc)
                        B[nt][kc] = *(const short8*)(wpk + WPK_CX2 +
                                                     ((nt * 16 + col) * 9 + t) * 64 +
                                                     kc * 32 + kq * 8);
#pragma unroll
                for (int i = 0; i < 5; ++i) {
                    int mt = wave + 8 * i;
                    if (mt >= 36) break;
                    int sr = mt >> 1;
                    int br2 = base - 1 + sr;
                    if ((unsigned)br2 > 31u) continue;
                    int tr = sr + dy;
                    int xs = ((mt & 1) << 4) + col + dx - 1;
                    bool xv = (unsigned)xs < 32u;
                    int xcl = xs < 0 ? 0 : (xs > 31 ? 31 : xs);
                    int p1 = tr * 32 + xcl;
#pragma unroll
                    for (int kc = 0; kc < 2; ++kc) {
                        int c = kc * 4 + kq;
                        short8 a = *(const short8*)(T1 + p1 * 64 + ((c ^ (p1 & 7)) << 3));
                        if (!xv) a = short8{0, 0, 0, 0, 0, 0, 0, 0};
#pragma unroll
                        for (int nt = 0; nt < 4; ++nt)
                            acc[i][nt] = __builtin_amdgcn_mfma_f32_16x16x32_bf16(
                                a, B[nt][kc], acc[i][nt], 0, 0, 0);
                    }
                }
            }
#pragma unroll
            for (int i = 0; i < 5; ++i) {
                int mt = wave + 8 * i;
                if (mt >= 36) break;
                int sr = mt >> 1;
                int br2 = base - 1 + sr;
                if ((unsigned)br2 > 31u) continue;
#pragma unroll
                for (int nt = 0; nt < 4; ++nt) {
                    int co = nt * 16 + col;
#pragma unroll
                    for (int r = 0; r < 4; ++r) {
                        int p2 = mt * 16 + kq * 4 + r;
                        T2[p2 * 64 + (((co >> 3) ^ (p2 & 7)) << 3) + (co & 7)] =
                            f2bfu(fmaxf(acc[i][nt][r], 0.f));
                    }
                }
            }
        }
        __syncthreads();
        // ---- phase 3: conv3 64->48 (T2) + pixel-shuffle/crop/clip -> out ----
        {
            f32x4 acc[4][3];
#pragma unroll
            for (int nt = 0; nt < 3; ++nt) {
                float bv = cx_b3[nt * 16 + col];
#pragma unroll
                for (int i = 0; i < 4; ++i) acc[i][nt] = f32x4{bv, bv, bv, bv};
            }
#pragma unroll 1
            for (int t = 0; t < 9; ++t) {
                int dy = t / 3, dx = t - dy * 3;
                short8 B[3][2];
#pragma unroll
                for (int nt = 0; nt < 3; ++nt)
#pragma unroll
                    for (int kc = 0; kc < 2; ++kc)
                        B[nt][kc] = *(const short8*)(wpk + WPK_CX3 +
                                                     ((nt * 16 + col) * 9 + t) * 64 +
                                                     kc * 32 + kq * 8);
#pragma unroll
                for (int i = 0; i < 4; ++i) {
                    int mt = wave + 8 * i;  // 0..31
                    int orow = mt >> 1;
                    int tr2 = orow + dy;
                    int xs = ((mt & 1) << 4) + col + dx - 1;
                    bool xv = (unsigned)xs < 32u;
                    int xcl = xs < 0 ? 0 : (xs > 31 ? 31 : xs);
                    int p2 = tr2 * 32 + xcl;
#pragma unroll
                    for (int kc = 0; kc < 2; ++kc) {
                        int c = kc * 4 + kq;
                        short8 a = *(const short8*)(T2 + p2 * 64 + ((c ^ (p2 & 7)) << 3));
                        if (!xv) a = short8{0, 0, 0, 0, 0, 0, 0, 0};
#pragma unroll
                        for (int nt = 0; nt < 3; ++nt)
                            acc[i][nt] = __builtin_amdgcn_mfma_f32_16x16x32_bf16(
                                a, B[nt][kc], acc[i][nt], 0, 0, 0);
                    }
                }
            }
#pragma unroll
            for (int i = 0; i < 4; ++i) {
                int mt = wave + 8 * i;
                int py = base + (mt >> 1);
#pragma unroll
                for (int nt = 0; nt < 3; ++nt) {
                    int co = nt * 16 + col;
                    int ch = co >> 4, dy2 = (co >> 2) & 3, dx2 = co & 3;
#pragma unroll
                    for (int r = 0; r < 4; ++r) {
                        int p = mt * 16 + kq * 4 + r;
                        int px = p & 31;
                        int r0 = py * 4 + dy2 - 24, s0 = px * 4 + dx2 - 24;
                        if ((unsigned)r0 < 80u && (unsigned)s0 < 80u) {
                            float v = fminf(fmaxf(acc[i][nt][r], 0.f), 1.f);
                            out[ch * 2457600 + (bh * 80 + r0) * 1280 + bw * 80 + s0] = v;
                        }
                    }
                }
            }
        }
    } else {
        // ---- lt: conv2 16->48 (T1) + pixel-shuffle/crop/clip -> out ----
        f32x4 acc[4][3];
#pragma unroll
        for (int nt = 0; nt < 3; ++nt) {
            float bv = lt_b2[nt * 16 + col];
#pragma unroll
            for (int i = 0; i < 4; ++i) acc[i][nt] = f32x4{bv, bv, bv, bv};
        }
#pragma unroll 1
        for (int t = 0; t < 9; ++t) {
            int dy = t / 3, dx = t - dy * 3;
            short8 B[3];
#pragma unroll
            for (int nt = 0; nt < 3; ++nt)
                B[nt] = *(const short8*)(wpk + WPK_LT2 +
                                         ((nt * 16 + col) * 9 + t) * 32 + kq * 8);
#pragma unroll
            for (int i = 0; i < 4; ++i) {
                int mt = wave + 8 * i;  // 0..31
                int orow = mt >> 1;
                int tr = orow + 1 + dy;
                int xs = ((mt & 1) << 4) + col + dx - 1;
                bool xv = (unsigned)xs < 32u;
                int xcl = xs < 0 ? 0 : (xs > 31 ? 31 : xs);
                int p1 = tr * 32 + xcl;
                short8 a = *(const short8*)(T1 + p1 * 32 + ((kq ^ ((p1 >> 1) & 3)) << 3));
                if (!xv) a = short8{0, 0, 0, 0, 0, 0, 0, 0};
#pragma unroll
                for (int nt = 0; nt < 3; ++nt)
                    acc[i][nt] = __builtin_amdgcn_mfma_f32_16x16x32_bf16(
                        a, B[nt], acc[i][nt], 0, 0, 0);
            }
        }
#pragma unroll
        for (int i = 0; i < 4; ++i) {
            int mt = wave + 8 * i;
            int py = base + (mt >> 1);
#pragma unroll
            for (int nt = 0; nt < 3; ++nt) {
                int co = nt * 16 + col;
                int ch = co >> 4, dy2 = (co >> 2) & 3, dx2 = co & 3;
#pragma unroll
                for (int r = 0; r < 4; ++r) {
                    int p = mt * 16 + kq * 4 + r;
                    int px = p & 31;
                    int r0 = py * 4 + dy2 - 24, s0 = px * 4 + dx2 - 24;
                    if ((unsigned)r0 < 80u && (unsigned)s0 < 80u) {
                        float v = fminf(fmaxf(acc[i][nt][r], 0.f), 1.f);
                        out[ch * 2457600 + (bh * 80 + r0) * 1280 + bw * 80 + s0] = v;
                    }
                }
            }
        }
    }
}

extern "C" void kernel_launch(void* const* d_in, const int* in_sizes, int n_in,
                              void* d_out, int out_size, void* d_ws, size_t ws_size,
                              hipStream_t stream) {
    const float* x      = (const float*)d_in[0];
    const float* cls_w1 = (const float*)d_in[1];
    const float* cls_b1 = (const float*)d_in[2];
    const float* cls_w2 = (const float*)d_in[3];
    const float* cls_b2 = (const float*)d_in[4];
    const float* cls_w3 = (const float*)d_in[5];
    const float* cls_b3 = (const float*)d_in[6];
    const float* cls_w4 = (const float*)d_in[7];
    const float* cls_b4 = (const float*)d_in[8];
    const float* cls_w5 = (const float*)d_in[9];
    const float* cls_b5 = (const float*)d_in[10];
    const float* lt_w1  = (const float*)d_in[11];
    const float* lt_b1  = (const float*)d_in[12];
    const float* lt_w2  = (const float*)d_in[13];
    const float* lt_b2  = (const float*)d_in[14];
    const float* cx_w1  = (const float*)d_in[15];
    const float* cx_b1  = (const float*)d_in[16];
    const float* cx_w2  = (const float*)d_in[17];
    const float* cx_b2  = (const float*)d_in[18];
    const float* cx_w3  = (const float*)d_in[19];
    const float* cx_b3  = (const float*)d_in[20];

    float* ws = (float*)d_ws;
    float* out = (float*)d_out;

    // persistent small buffers
    size_t off = 0;
    float* c2 = ws + off;   off += (size_t)32 * HW2;
    float* c4 = ws + off;   off += (size_t)8 * HW4;
    float* clsv = ws + off; off += 384;
    unsigned short* wpk = (unsigned short*)(ws + off); off += (WPK_ALL + 1) / 2;
    size_t fixed = off;

    // scratch: c1 split planes + p3 (classifier phase only)
    unsigned short* c1s = (unsigned short*)(ws + fixed);   // 96*HW shorts
    float* p3 = ws + fixed + (size_t)48 * HW;              // 32*HW2 floats

    (void)hipFuncSetAttribute((const void*)k_cls2m,
                              hipFuncAttributeMaxDynamicSharedMemorySize, 32896);
    (void)hipFuncSetAttribute((const void*)k_block,
                              hipFuncAttributeMaxDynamicSharedMemorySize, 159728);

    k_pack<<<(WPK_ALL + 255) / 256, 256, 0, stream>>>(cx_w2, cx_w3, lt_w2, cx_w1, lt_w1,
                                                      cls_w2, wpk);
    k_cls1s<<<dim3((HW + 255) / 256, 4), 256, 0, stream>>>(x, cls_w1, cls_b1, c1s);
    k_cls2m<<<600, 256, 32896, stream>>>(c1s, wpk, cls_b2, c2);
    k_cls3<<<dim3(150, 2, 2), 256, 0, stream>>>(c2, cls_w3, cls_b3, p3);
    k_cls4f<<<150, 256, 0, stream>>>(p3, cls_w4, cls_b4, c4);
    k_cls5<<<1, 384, 0, stream>>>(c4, cls_w5, cls_b5, clsv, out + IMG_PIX);
    k_block<<<NB * 2, 512, 159728, stream>>>(x, wpk, lt_b1, cx_b1, lt_b2, cx_b2,
                                             cx_b3, clsv, out);
}